// Round 1
// baseline (3153.409 us; speedup 1.0000x reference)
//
#include <hip/hip_runtime.h>
#include <hip/hip_bf16.h>

// Problem constants
#define B_   8
#define NH_  8
#define HC_  32
#define NG_  4
#define NC_  256
#define CG_  64
#define H_   64
#define W_   64
#define HW_  4096
#define KM_  9
#define NS_  2048
#define DIMO_ 256
#define SCALE_ 0.17677669529663687f  // 32^-0.5

__device__ __forceinline__ float gelu_f(float v) {
    return 0.5f * v * (1.0f + erff(v * 0.70710678118654752f));
}

template<int ACT>
__device__ __forceinline__ float act_f(float v) {
    if constexpr (ACT == 1) return gelu_f(v);
    else if constexpr (ACT == 2) return fmaxf(v, 0.0f);
    else return v;
}

// ---------------------------------------------------------------------------
// GEMM, channel-major X: Y[b,o,p] = act(sum_c X[b,c,p]*W[o,c] + bias[o])
// X: (NB, Cin, P), W: (Cout, Cin), Y: (NB, Cout, P)
// grid: (P/64, Cout/64, NB), block 256
// ---------------------------------------------------------------------------
template<int ACT>
__global__ __launch_bounds__(256) void gemm_cp(
    const float* __restrict__ X, const float* __restrict__ W,
    const float* __restrict__ bias, float* __restrict__ Y,
    int Cin, int Cout, int P)
{
    int b = blockIdx.z;
    int p0 = blockIdx.x * 64;
    int o0 = blockIdx.y * 64;
    const float* Xb = X + (size_t)b * Cin * P;
    float* Yb = Y + (size_t)b * Cout * P;
    __shared__ float Xs[16][64];
    __shared__ float Ws[16][65];
    int tid = threadIdx.x;
    int tx = tid & 15, ty = tid >> 4;
    float acc[4][4] = {};
    for (int c0 = 0; c0 < Cin; c0 += 16) {
        for (int e = tid; e < 1024; e += 256) {
            int cc = e >> 6, pp = e & 63;
            Xs[cc][pp] = Xb[(size_t)(c0 + cc) * P + p0 + pp];
        }
        for (int e = tid; e < 1024; e += 256) {
            int oo = e >> 4, cc = e & 15;
            Ws[cc][oo] = W[(size_t)(o0 + oo) * Cin + c0 + cc];
        }
        __syncthreads();
        #pragma unroll
        for (int cc = 0; cc < 16; ++cc) {
            float a[4], bb[4];
            #pragma unroll
            for (int i = 0; i < 4; ++i) a[i] = Ws[cc][ty * 4 + i];
            #pragma unroll
            for (int j = 0; j < 4; ++j) bb[j] = Xs[cc][tx * 4 + j];
            #pragma unroll
            for (int i = 0; i < 4; ++i)
                #pragma unroll
                for (int j = 0; j < 4; ++j)
                    acc[i][j] += a[i] * bb[j];
        }
        __syncthreads();
    }
    #pragma unroll
    for (int i = 0; i < 4; ++i) {
        int o = o0 + ty * 4 + i;
        float bvv = bias[o];
        #pragma unroll
        for (int j = 0; j < 4; ++j) {
            int p = p0 + tx * 4 + j;
            Yb[(size_t)o * P + p] = act_f<ACT>(acc[i][j] + bvv);
        }
    }
}

// ---------------------------------------------------------------------------
// GEMM, row-major X: Y[r,o] = act(sum_c X[r,c]*W[o,c] + bias[o])
// X: (R, Cin), W: (Cout, Cin), Y: (R, Cout)
// grid: (R/64, Cout/64), block 256
// ---------------------------------------------------------------------------
template<int ACT>
__global__ __launch_bounds__(256) void gemm_rm(
    const float* __restrict__ X, const float* __restrict__ W,
    const float* __restrict__ bias, float* __restrict__ Y,
    int Cin, int Cout, int R)
{
    int r0 = blockIdx.x * 64;
    int o0 = blockIdx.y * 64;
    __shared__ float Xs[16][65];
    __shared__ float Ws[16][65];
    int tid = threadIdx.x;
    int tx = tid & 15, ty = tid >> 4;
    float acc[4][4] = {};
    for (int c0 = 0; c0 < Cin; c0 += 16) {
        for (int e = tid; e < 1024; e += 256) {
            int rr = e >> 4, cc = e & 15;
            Xs[cc][rr] = X[(size_t)(r0 + rr) * Cin + c0 + cc];
        }
        for (int e = tid; e < 1024; e += 256) {
            int oo = e >> 4, cc = e & 15;
            Ws[cc][oo] = W[(size_t)(o0 + oo) * Cin + c0 + cc];
        }
        __syncthreads();
        #pragma unroll
        for (int cc = 0; cc < 16; ++cc) {
            float a[4], bb[4];
            #pragma unroll
            for (int i = 0; i < 4; ++i) a[i] = Ws[cc][ty * 4 + i];
            #pragma unroll
            for (int j = 0; j < 4; ++j) bb[j] = Xs[cc][tx * 4 + j];
            #pragma unroll
            for (int i = 0; i < 4; ++i)
                #pragma unroll
                for (int j = 0; j < 4; ++j)
                    acc[i][j] += a[i] * bb[j];
        }
        __syncthreads();
    }
    #pragma unroll
    for (int j = 0; j < 4; ++j) {
        int r = r0 + tx * 4 + j;
        #pragma unroll
        for (int i = 0; i < 4; ++i) {
            int o = o0 + ty * 4 + i;
            Y[(size_t)r * Cout + o] = act_f<ACT>(acc[i][j] + bias[o]);
        }
    }
}

// ---------------------------------------------------------------------------
// Depthwise 3x3 SAME + bias + GELU.  qf viewed as (B*NG, CG, H, W), same flat
// layout as (B, NC, H, W).  One thread per output element.
// ---------------------------------------------------------------------------
__global__ __launch_bounds__(256) void dwconv_kernel(
    const float* __restrict__ qf, const float* __restrict__ W_dw,
    const float* __restrict__ b_dw, float* __restrict__ h)
{
    int f = blockIdx.x * 256 + threadIdx.x;   // < 32*64*4096
    int x = f & 63;
    int y = (f >> 6) & 63;
    int cc = (f >> 12) & 63;
    int bg = f >> 18;
    const float* qp = qf + ((size_t)(bg * 64 + cc) << 12);
    float acc = b_dw[cc];
    #pragma unroll
    for (int ky = 0; ky < 3; ++ky) {
        int yy = y + ky - 1;
        if (yy < 0 || yy > 63) continue;
        #pragma unroll
        for (int kx = 0; kx < 3; ++kx) {
            int xx = x + kx - 1;
            if (xx < 0 || xx > 63) continue;
            acc += W_dw[cc * 9 + ky * 3 + kx] * qp[yy * 64 + xx];
        }
    }
    h[f] = gelu_f(acc);
}

// ---------------------------------------------------------------------------
// Offsets -> sampling positions at the NS gathered locations only.
// pos[((bg*KM+km)*NS+n)*2 + {0:y,1:x}]
// grid: (NS/256, B*NG), block 256
// ---------------------------------------------------------------------------
__global__ __launch_bounds__(256) void pos_kernel(
    const float* __restrict__ h, const int* __restrict__ idx,
    const float* __restrict__ W_pw, float* __restrict__ pos)
{
    int bg = blockIdx.y;
    int n = blockIdx.x * 256 + threadIdx.x;
    __shared__ float wpw[18 * 64];
    for (int e = threadIdx.x; e < 18 * 64; e += 256) wpw[e] = W_pw[e];
    __syncthreads();
    int yn = idx[2 * n], xn = idx[2 * n + 1];
    const float* hp = h + ((size_t)bg << 18) + yn * 64 + xn;  // bg*64*4096
    float off[18] = {};
    for (int cc = 0; cc < 64; ++cc) {
        float hv = hp[cc * 4096];
        #pragma unroll
        for (int o = 0; o < 18; ++o) off[o] += wpw[o * 64 + cc] * hv;
    }
    #pragma unroll
    for (int km = 0; km < 9; ++km) {
        int ky = km / 3, kx = km % 3;
        int yc = yn + ky - 1; yc = yc < 0 ? 0 : (yc > 63 ? 63 : yc);
        int xc = xn + kx - 1; xc = xc < 0 ? 0 : (xc > 63 ? 63 : xc);
        float py = tanhf(off[2 * km])     * 0.03125f + ((yc + 0.5f) * 0.03125f - 1.0f);
        float px = tanhf(off[2 * km + 1]) * 0.03125f + ((xc + 0.5f) * 0.03125f - 1.0f);
        size_t pb = (((size_t)bg * 9 + km) * 2048 + n) * 2;
        pos[pb] = py;
        pos[pb + 1] = px;
    }
}

// ---------------------------------------------------------------------------
// q gather: q[b,c,n] = qf[b,c,idx[n]]
// ---------------------------------------------------------------------------
__global__ __launch_bounds__(256) void qgather_kernel(
    const float* __restrict__ qf, const int* __restrict__ idx,
    float* __restrict__ q)
{
    int f = blockIdx.x * 256 + threadIdx.x;  // < 4194304
    int n = f & 2047;
    int c = (f >> 11) & 255;
    int b = f >> 19;
    int yn = idx[2 * n], xn = idx[2 * n + 1];
    q[f] = qf[(((size_t)b * 256 + c) << 12) + yn * 64 + xn];
}

// ---------------------------------------------------------------------------
// Bilinear sample at gathered positions -> x_sampled (B, NC, KM, NS)
// ---------------------------------------------------------------------------
__global__ __launch_bounds__(256) void sample_kernel(
    const float* __restrict__ x1, const float* __restrict__ pos,
    float* __restrict__ xsamp)
{
    size_t f = (size_t)blockIdx.x * 256 + threadIdx.x;  // < 37748736
    int n = (int)(f & 2047);
    int km = (int)((f >> 11) % 9);
    int bc = (int)(f / 18432);
    int c = bc & 255;
    int b = bc >> 8;
    int bg = b * 4 + (c >> 6);
    size_t pb = (((size_t)bg * 9 + km) * 2048 + n) * 2;
    float py = pos[pb], px = pos[pb + 1];
    float ix = (px + 1.0f) * 31.5f;
    float iy = (py + 1.0f) * 31.5f;
    float x0f = floorf(ix), y0f = floorf(iy);
    float wx = ix - x0f, wy = iy - y0f;
    const float* img = x1 + (((size_t)b * 256 + c) << 12);
    float v = 0.0f;
    #pragma unroll
    for (int dy = 0; dy < 2; ++dy) {
        float yf = y0f + dy;
        if (yf < 0.0f || yf > 63.0f) continue;
        float wyy = dy ? wy : 1.0f - wy;
        #pragma unroll
        for (int dx = 0; dx < 2; ++dx) {
            float xf = x0f + dx;
            if (xf < 0.0f || xf > 63.0f) continue;
            float wxx = dx ? wx : 1.0f - wx;
            v += wyy * wxx * img[(int)yf * 64 + (int)xf];
        }
    }
    xsamp[f] = v;
}

// ---------------------------------------------------------------------------
// Fused K/V projection + softmax(over 9) + PV.  One block per (b, n).
// out row-major (B*NS, NC); attn_full (B*NH, NS, KM) for deterministic mean.
// ---------------------------------------------------------------------------
__global__ __launch_bounds__(256) void attn_kernel(
    const float* __restrict__ xs, const float* __restrict__ q,
    const float* __restrict__ Wk, const float* __restrict__ bk,
    const float* __restrict__ Wv, const float* __restrict__ bv,
    float* __restrict__ out, float* __restrict__ attn_full)
{
    int b = blockIdx.x >> 11;
    int n = blockIdx.x & 2047;
    int o = threadIdx.x;
    __shared__ float xs_s[256][9];
    __shared__ float q_s[256];
    #pragma unroll
    for (int km = 0; km < 9; ++km)
        xs_s[o][km] = xs[(((size_t)(b * 256 + o) * 9 + km) << 11) + n];
    q_s[o] = q[(((size_t)b * 256 + o) << 11) + n];
    __syncthreads();

    float kx[9], vx[9];
    float bko = bk[o], bvo = bv[o];
    #pragma unroll
    for (int km = 0; km < 9; ++km) { kx[km] = bko; vx[km] = bvo; }
    const float4* wk4 = (const float4*)(Wk + (size_t)o * 256);
    const float4* wv4 = (const float4*)(Wv + (size_t)o * 256);
    for (int c4 = 0; c4 < 64; ++c4) {
        float4 wk = wk4[c4];
        float4 wv = wv4[c4];
        int c = c4 * 4;
        #pragma unroll
        for (int km = 0; km < 9; ++km) {
            float x0 = xs_s[c][km], x1v = xs_s[c + 1][km];
            float x2 = xs_s[c + 2][km], x3 = xs_s[c + 3][km];
            kx[km] += wk.x * x0 + wk.y * x1v + wk.z * x2 + wk.w * x3;
            vx[km] += wv.x * x0 + wv.y * x1v + wv.z * x2 + wv.w * x3;
        }
    }
    // per-head score reduction over the 32 channels of this head
    float s[9];
    float qo = q_s[o];
    #pragma unroll
    for (int km = 0; km < 9; ++km) s[km] = qo * kx[km];
    #pragma unroll
    for (int off = 16; off >= 1; off >>= 1)
        #pragma unroll
        for (int km = 0; km < 9; ++km)
            s[km] += __shfl_xor(s[km], off, 64);
    float m = s[0] * SCALE_;
    #pragma unroll
    for (int km = 0; km < 9; ++km) { s[km] *= SCALE_; m = fmaxf(m, s[km]); }
    float den = 0.0f;
    float a[9];
    #pragma unroll
    for (int km = 0; km < 9; ++km) { a[km] = expf(s[km] - m); den += a[km]; }
    float inv = 1.0f / den;
    #pragma unroll
    for (int km = 0; km < 9; ++km) a[km] *= inv;

    if ((o & 31) == 0) {
        int hd = o >> 5;
        size_t ab = (((size_t)(b * 8 + hd) << 11) + n) * 9;
        #pragma unroll
        for (int km = 0; km < 9; ++km) attn_full[ab + km] = a[km];
    }
    float ov = 0.0f;
    #pragma unroll
    for (int km = 0; km < 9; ++km) ov += a[km] * vx[km];
    out[(((size_t)b << 11) + n) * 256 + o] = ov;
}

// attn.mean(0) -> (NS, KM), deterministic
__global__ __launch_bounds__(256) void attn_reduce_kernel(
    const float* __restrict__ attf, float* __restrict__ o_attn)
{
    int e = blockIdx.x * 256 + threadIdx.x;  // < 18432
    int n = e / 9, km = e % 9;
    float sum = 0.0f;
    for (int bh = 0; bh < 64; ++bh)
        sum += attf[(((size_t)bh << 11) + n) * 9 + km];
    o_attn[e] = sum * (1.0f / 64.0f);
}

// pred_loc = l2 @ Wl3^T + bl3  (Cout=2)
__global__ __launch_bounds__(256) void loc_kernel(
    const float* __restrict__ l2, const float* __restrict__ Wl3,
    const float* __restrict__ bl3, float* __restrict__ o_loc)
{
    int f = blockIdx.x * 256 + threadIdx.x;  // < 32768
    int r = f >> 1, o = f & 1;
    const float4* row = (const float4*)(l2 + (size_t)r * 256);
    const float4* wr = (const float4*)(Wl3 + (size_t)o * 256);
    float sum = bl3[o];
    for (int c = 0; c < 64; ++c) {
        float4 a = row[c], w = wr[c];
        sum += a.x * w.x + a.y * w.y + a.z * w.z + a.w * w.w;
    }
    o_loc[f] = sum;
}

// deterministic two-stage loss reductions
__global__ __launch_bounds__(256) void loss_cls_partial(
    const float* __restrict__ pred, const int* __restrict__ labels,
    float* __restrict__ partial)
{
    int tid = threadIdx.x;
    float sum = 0.0f;
    for (int e = blockIdx.x * 256 + tid; e < 4194304; e += 65536) {
        int r = e >> 8, j = e & 255;
        float p = pred[e];
        float t = (labels[r] == j) ? 1.0f : 0.0f;
        sum += fmaxf(p, 0.0f) - p * t + log1pf(expf(-fabsf(p)));
    }
    __shared__ float red[256];
    red[tid] = sum;
    __syncthreads();
    for (int w = 128; w > 0; w >>= 1) {
        if (tid < w) red[tid] += red[tid + w];
        __syncthreads();
    }
    if (tid == 0) partial[blockIdx.x] = red[0];
}

__global__ __launch_bounds__(256) void loss_loc_partial(
    const float* __restrict__ pred, const float* __restrict__ coords,
    float* __restrict__ partial)
{
    int tid = threadIdx.x;
    float sum = 0.0f;
    for (int e = blockIdx.x * 256 + tid; e < 32768; e += 65536)
        sum += fabsf(pred[e] - coords[e]);
    __shared__ float red[256];
    red[tid] = sum;
    __syncthreads();
    for (int w = 128; w > 0; w >>= 1) {
        if (tid < w) red[tid] += red[tid + w];
        __syncthreads();
    }
    if (tid == 0) partial[blockIdx.x] = red[0];
}

__global__ __launch_bounds__(256) void loss_final(
    const float* __restrict__ part, float* __restrict__ out)
{
    __shared__ float red[256];
    int t = threadIdx.x;
    red[t] = part[t];
    __syncthreads();
    for (int w = 128; w > 0; w >>= 1) {
        if (t < w) red[t] += red[t + w];
        __syncthreads();
    }
    if (t == 0) out[0] = red[0] * (1.0f / 4194304.0f);
    __syncthreads();
    red[t] = part[256 + t];
    __syncthreads();
    for (int w = 128; w > 0; w >>= 1) {
        if (t < w) red[t] += red[t + w];
        __syncthreads();
    }
    if (t == 0) out[1] = red[0] * (1.0f / 32768.0f);
}

extern "C" void kernel_launch(void* const* d_in, const int* in_sizes, int n_in,
                              void* d_out, int out_size, void* d_ws, size_t ws_size,
                              hipStream_t stream) {
    const float* x     = (const float*)d_in[0];
    const int*   idx   = (const int*)d_in[1];
    const int*   labels= (const int*)d_in[2];
    const float* coords= (const float*)d_in[3];
    const float* W_ip  = (const float*)d_in[4];
    const float* b_ip  = (const float*)d_in[5];
    const float* Wq    = (const float*)d_in[6];
    const float* bq    = (const float*)d_in[7];
    const float* Wk    = (const float*)d_in[8];
    const float* bk    = (const float*)d_in[9];
    const float* Wv    = (const float*)d_in[10];
    const float* bv    = (const float*)d_in[11];
    const float* W_dw  = (const float*)d_in[12];
    const float* b_dw  = (const float*)d_in[13];
    const float* W_pw  = (const float*)d_in[14];
    const float* Wc1   = (const float*)d_in[15];
    const float* bc1   = (const float*)d_in[16];
    const float* Wc2   = (const float*)d_in[17];
    const float* bc2   = (const float*)d_in[18];
    const float* Wc3   = (const float*)d_in[19];
    const float* bc3   = (const float*)d_in[20];
    const float* Wl1   = (const float*)d_in[21];
    const float* bl1   = (const float*)d_in[22];
    const float* Wl2   = (const float*)d_in[23];
    const float* bl2   = (const float*)d_in[24];
    const float* Wl3   = (const float*)d_in[25];
    const float* bl3   = (const float*)d_in[26];

    float* out = (float*)d_out;
    float* ws  = (float*)d_ws;

    float* bufA = ws;                 // x1, then h2, then l2      (8388608)
    float* bufB = ws + 8388608;       // qf, then attn-out         (8388608)
    float* bufC = ws + 16777216;      // h, then h1, then l1       (8388608)
    float* posb = ws + 25165824;      // positions                 (1179648)
    float* qg   = ws + 26345472;      // gathered q                (4194304)
    float* attf = ws + 30539776;      // full attn                 (1179648)
    float* part = ws + 31719424;      // loss partials             (512)

    float* o_xs   = out + 2;
    float* o_cls  = out + 37748738;
    float* o_loc  = out + 41943042;
    float* o_attn = out + 41975810;

    // 1. x1 = gelu(x @ W_ip^T + b_ip)
    gemm_cp<1><<<dim3(64, 4, 8), 256, 0, stream>>>(x, W_ip, b_ip, bufA, 256, 256, 4096);
    // 2. qf = x1 @ Wq^T + bq
    gemm_cp<0><<<dim3(64, 4, 8), 256, 0, stream>>>(bufA, Wq, bq, bufB, 256, 256, 4096);
    // 3. h = gelu(dwconv3x3(qf) + b_dw)
    dwconv_kernel<<<32768, 256, 0, stream>>>(bufB, W_dw, b_dw, bufC);
    // 4. sampling positions at gathered idx
    pos_kernel<<<dim3(8, 32), 256, 0, stream>>>(bufC, idx, W_pw, posb);
    // 5. q gather
    qgather_kernel<<<16384, 256, 0, stream>>>(bufB, idx, qg);
    // 6. bilinear sample -> x_sampled (output)
    sample_kernel<<<147456, 256, 0, stream>>>(bufA, posb, o_xs);
    // 7. fused attention -> out (bufB), attn_full
    attn_kernel<<<16384, 256, 0, stream>>>(o_xs, qg, Wk, bk, Wv, bv, bufB, attf);
    // 8. attn mean (deterministic)
    attn_reduce_kernel<<<72, 256, 0, stream>>>(attf, o_attn);
    // 9-11. cls MLP
    gemm_rm<2><<<dim3(256, 4), 256, 0, stream>>>(bufB, Wc1, bc1, bufC, 256, 256, 16384);
    gemm_rm<2><<<dim3(256, 4), 256, 0, stream>>>(bufC, Wc2, bc2, bufA, 256, 256, 16384);
    gemm_rm<0><<<dim3(256, 4), 256, 0, stream>>>(bufA, Wc3, bc3, o_cls, 256, 256, 16384);
    // 12-14. loc MLP
    gemm_rm<2><<<dim3(256, 4), 256, 0, stream>>>(bufB, Wl1, bl1, bufC, 256, 256, 16384);
    gemm_rm<2><<<dim3(256, 4), 256, 0, stream>>>(bufC, Wl2, bl2, bufA, 256, 256, 16384);
    loc_kernel<<<128, 256, 0, stream>>>(bufA, Wl3, bl3, o_loc);
    // 15-17. losses (deterministic two-stage)
    loss_cls_partial<<<256, 256, 0, stream>>>(o_cls, labels, part);
    loss_loc_partial<<<256, 256, 0, stream>>>(o_loc, coords, part + 256);
    loss_final<<<1, 256, 0, stream>>>(part, out);
}

// Round 2
// 1293.930 us; speedup vs baseline: 2.4371x; 2.4371x over previous
//
#include <hip/hip_runtime.h>
#include <hip/hip_bf16.h>

// Problem constants
#define B_   8
#define NH_  8
#define HC_  32
#define NG_  4
#define NC_  256
#define CG_  64
#define H_   64
#define W_   64
#define HW_  4096
#define KM_  9
#define NS_  2048
#define DIMO_ 256
#define SCALE_ 0.17677669529663687f  // 32^-0.5

__device__ __forceinline__ float gelu_f(float v) {
    return 0.5f * v * (1.0f + erff(v * 0.70710678118654752f));
}

template<int ACT>
__device__ __forceinline__ float act_f(float v) {
    if constexpr (ACT == 1) return gelu_f(v);
    else if constexpr (ACT == 2) return fmaxf(v, 0.0f);
    else return v;
}

__device__ __forceinline__ unsigned short f2bf(float f) {
    __hip_bfloat16 hb = __float2bfloat16(f);
    return *reinterpret_cast<unsigned short*>(&hb);
}
__device__ __forceinline__ float bf2f(unsigned short u) {
    unsigned int ui = ((unsigned int)u) << 16;
    float f;
    __builtin_memcpy(&f, &ui, 4);
    return f;
}

// ---------------------------------------------------------------------------
// GEMM, channel-major X: Y[b,o,p] = act(sum_c X[b,c,p]*W[o,c] + bias[o])
// ---------------------------------------------------------------------------
template<int ACT>
__global__ __launch_bounds__(256) void gemm_cp(
    const float* __restrict__ X, const float* __restrict__ W,
    const float* __restrict__ bias, float* __restrict__ Y,
    int Cin, int Cout, int P)
{
    int b = blockIdx.z;
    int p0 = blockIdx.x * 64;
    int o0 = blockIdx.y * 64;
    const float* Xb = X + (size_t)b * Cin * P;
    float* Yb = Y + (size_t)b * Cout * P;
    __shared__ float Xs[16][64];
    __shared__ float Ws[16][65];
    int tid = threadIdx.x;
    int tx = tid & 15, ty = tid >> 4;
    float acc[4][4] = {};
    for (int c0 = 0; c0 < Cin; c0 += 16) {
        for (int e = tid; e < 1024; e += 256) {
            int cc = e >> 6, pp = e & 63;
            Xs[cc][pp] = Xb[(size_t)(c0 + cc) * P + p0 + pp];
        }
        for (int e = tid; e < 1024; e += 256) {
            int oo = e >> 4, cc = e & 15;
            Ws[cc][oo] = W[(size_t)(o0 + oo) * Cin + c0 + cc];
        }
        __syncthreads();
        #pragma unroll
        for (int cc = 0; cc < 16; ++cc) {
            float a[4], bb[4];
            #pragma unroll
            for (int i = 0; i < 4; ++i) a[i] = Ws[cc][ty * 4 + i];
            #pragma unroll
            for (int j = 0; j < 4; ++j) bb[j] = Xs[cc][tx * 4 + j];
            #pragma unroll
            for (int i = 0; i < 4; ++i)
                #pragma unroll
                for (int j = 0; j < 4; ++j)
                    acc[i][j] += a[i] * bb[j];
        }
        __syncthreads();
    }
    #pragma unroll
    for (int i = 0; i < 4; ++i) {
        int o = o0 + ty * 4 + i;
        float bvv = bias[o];
        #pragma unroll
        for (int j = 0; j < 4; ++j) {
            int p = p0 + tx * 4 + j;
            Yb[(size_t)o * P + p] = act_f<ACT>(acc[i][j] + bvv);
        }
    }
}

// ---------------------------------------------------------------------------
// GEMM, row-major X: Y[r,o] = act(sum_c X[r,c]*W[o,c] + bias[o])
// ---------------------------------------------------------------------------
template<int ACT>
__global__ __launch_bounds__(256) void gemm_rm(
    const float* __restrict__ X, const float* __restrict__ W,
    const float* __restrict__ bias, float* __restrict__ Y,
    int Cin, int Cout, int R)
{
    int r0 = blockIdx.x * 64;
    int o0 = blockIdx.y * 64;
    __shared__ float Xs[16][65];
    __shared__ float Ws[16][65];
    int tid = threadIdx.x;
    int tx = tid & 15, ty = tid >> 4;
    float acc[4][4] = {};
    for (int c0 = 0; c0 < Cin; c0 += 16) {
        for (int e = tid; e < 1024; e += 256) {
            int rr = e >> 4, cc = e & 15;
            Xs[cc][rr] = X[(size_t)(r0 + rr) * Cin + c0 + cc];
        }
        for (int e = tid; e < 1024; e += 256) {
            int oo = e >> 4, cc = e & 15;
            Ws[cc][oo] = W[(size_t)(o0 + oo) * Cin + c0 + cc];
        }
        __syncthreads();
        #pragma unroll
        for (int cc = 0; cc < 16; ++cc) {
            float a[4], bb[4];
            #pragma unroll
            for (int i = 0; i < 4; ++i) a[i] = Ws[cc][ty * 4 + i];
            #pragma unroll
            for (int j = 0; j < 4; ++j) bb[j] = Xs[cc][tx * 4 + j];
            #pragma unroll
            for (int i = 0; i < 4; ++i)
                #pragma unroll
                for (int j = 0; j < 4; ++j)
                    acc[i][j] += a[i] * bb[j];
        }
        __syncthreads();
    }
    #pragma unroll
    for (int j = 0; j < 4; ++j) {
        int r = r0 + tx * 4 + j;
        #pragma unroll
        for (int i = 0; i < 4; ++i) {
            int o = o0 + ty * 4 + i;
            Y[(size_t)r * Cout + o] = act_f<ACT>(acc[i][j] + bias[o]);
        }
    }
}

// ---------------------------------------------------------------------------
// Depthwise 3x3 SAME + bias + GELU
// ---------------------------------------------------------------------------
__global__ __launch_bounds__(256) void dwconv_kernel(
    const float* __restrict__ qf, const float* __restrict__ W_dw,
    const float* __restrict__ b_dw, float* __restrict__ h)
{
    int f = blockIdx.x * 256 + threadIdx.x;
    int x = f & 63;
    int y = (f >> 6) & 63;
    int cc = (f >> 12) & 63;
    int bg = f >> 18;
    const float* qp = qf + ((size_t)(bg * 64 + cc) << 12);
    float acc = b_dw[cc];
    #pragma unroll
    for (int ky = 0; ky < 3; ++ky) {
        int yy = y + ky - 1;
        if (yy < 0 || yy > 63) continue;
        #pragma unroll
        for (int kx = 0; kx < 3; ++kx) {
            int xx = x + kx - 1;
            if (xx < 0 || xx > 63) continue;
            acc += W_dw[cc * 9 + ky * 3 + kx] * qp[yy * 64 + xx];
        }
    }
    h[f] = gelu_f(acc);
}

// ---------------------------------------------------------------------------
// Offsets -> sampling positions at the NS gathered locations only
// ---------------------------------------------------------------------------
__global__ __launch_bounds__(256) void pos_kernel(
    const float* __restrict__ h, const int* __restrict__ idx,
    const float* __restrict__ W_pw, float* __restrict__ pos)
{
    int bg = blockIdx.y;
    int n = blockIdx.x * 256 + threadIdx.x;
    __shared__ float wpw[18 * 64];
    for (int e = threadIdx.x; e < 18 * 64; e += 256) wpw[e] = W_pw[e];
    __syncthreads();
    int yn = idx[2 * n], xn = idx[2 * n + 1];
    const float* hp = h + ((size_t)bg << 18) + yn * 64 + xn;
    float off[18] = {};
    for (int cc = 0; cc < 64; ++cc) {
        float hv = hp[cc * 4096];
        #pragma unroll
        for (int o = 0; o < 18; ++o) off[o] += wpw[o * 64 + cc] * hv;
    }
    #pragma unroll
    for (int km = 0; km < 9; ++km) {
        int ky = km / 3, kx = km % 3;
        int yc = yn + ky - 1; yc = yc < 0 ? 0 : (yc > 63 ? 63 : yc);
        int xc = xn + kx - 1; xc = xc < 0 ? 0 : (xc > 63 ? 63 : xc);
        float py = tanhf(off[2 * km])     * 0.03125f + ((yc + 0.5f) * 0.03125f - 1.0f);
        float px = tanhf(off[2 * km + 1]) * 0.03125f + ((xc + 0.5f) * 0.03125f - 1.0f);
        size_t pb = (((size_t)bg * 9 + km) * 2048 + n) * 2;
        pos[pb] = py;
        pos[pb + 1] = px;
    }
}

// ---------------------------------------------------------------------------
// q gather: q[b,c,n] = qf[b,c,idx[n]]
// ---------------------------------------------------------------------------
__global__ __launch_bounds__(256) void qgather_kernel(
    const float* __restrict__ qf, const int* __restrict__ idx,
    float* __restrict__ q)
{
    int f = blockIdx.x * 256 + threadIdx.x;
    int n = f & 2047;
    int c = (f >> 11) & 255;
    int b = f >> 19;
    int yn = idx[2 * n], xn = idx[2 * n + 1];
    q[f] = qf[(((size_t)b * 256 + c) << 12) + yn * 64 + xn];
}

// ---------------------------------------------------------------------------
// Bilinear sample at gathered positions -> x_sampled (B, NC, KM, NS)
// ---------------------------------------------------------------------------
__global__ __launch_bounds__(256) void sample_kernel(
    const float* __restrict__ x1, const float* __restrict__ pos,
    float* __restrict__ xsamp)
{
    size_t f = (size_t)blockIdx.x * 256 + threadIdx.x;
    int n = (int)(f & 2047);
    int km = (int)((f >> 11) % 9);
    int bc = (int)(f / 18432);
    int c = bc & 255;
    int b = bc >> 8;
    int bg = b * 4 + (c >> 6);
    size_t pb = (((size_t)bg * 9 + km) * 2048 + n) * 2;
    float py = pos[pb], px = pos[pb + 1];
    float ix = (px + 1.0f) * 31.5f;
    float iy = (py + 1.0f) * 31.5f;
    float x0f = floorf(ix), y0f = floorf(iy);
    float wx = ix - x0f, wy = iy - y0f;
    const float* img = x1 + (((size_t)b * 256 + c) << 12);
    float v = 0.0f;
    #pragma unroll
    for (int dy = 0; dy < 2; ++dy) {
        float yf = y0f + dy;
        if (yf < 0.0f || yf > 63.0f) continue;
        float wyy = dy ? wy : 1.0f - wy;
        #pragma unroll
        for (int dx = 0; dx < 2; ++dx) {
            float xf = x0f + dx;
            if (xf < 0.0f || xf > 63.0f) continue;
            float wxx = dx ? wx : 1.0f - wx;
            v += wyy * wxx * img[(int)yf * 64 + (int)xf];
        }
    }
    xsamp[f] = v;
}

// ---------------------------------------------------------------------------
// qk[b,h,c,n] = sum_j q[b,h*32+j,n] * Wk[h*32+j,c]  (stored bf16)
// grid: (n-tiles=32, c-tiles=4, bh=64), block 256
// ---------------------------------------------------------------------------
__global__ __launch_bounds__(256) void qk_kernel(
    const float* __restrict__ qg, const float* __restrict__ Wk,
    unsigned short* __restrict__ qkb)
{
    int bh = blockIdx.z;
    int b = bh >> 3, h = bh & 7;
    int c0 = blockIdx.y * 64;
    int n0 = blockIdx.x * 64;
    __shared__ float Qs[32][64];
    __shared__ float Ws[32][65];
    int tid = threadIdx.x;
    for (int e = tid; e < 2048; e += 256) {
        int j = e >> 6, nn = e & 63;
        Qs[j][nn] = qg[(((size_t)(b * 256 + h * 32 + j)) << 11) + n0 + nn];
    }
    for (int e = tid; e < 2048; e += 256) {
        int j = e >> 6, cc = e & 63;
        Ws[j][cc] = Wk[(size_t)(h * 32 + j) * 256 + c0 + cc];
    }
    __syncthreads();
    int tx = tid & 15, ty = tid >> 4;
    float acc[4][4] = {};
    #pragma unroll
    for (int j = 0; j < 32; ++j) {
        float a[4], bb[4];
        #pragma unroll
        for (int i = 0; i < 4; ++i) a[i] = Ws[j][ty * 4 + i];
        #pragma unroll
        for (int k = 0; k < 4; ++k) bb[k] = Qs[j][tx * 4 + k];
        #pragma unroll
        for (int i = 0; i < 4; ++i)
            #pragma unroll
            for (int k = 0; k < 4; ++k)
                acc[i][k] += a[i] * bb[k];
    }
    #pragma unroll
    for (int i = 0; i < 4; ++i) {
        int c = c0 + ty * 4 + i;
        ushort4 pk;
        pk.x = f2bf(acc[i][0]); pk.y = f2bf(acc[i][1]);
        pk.z = f2bf(acc[i][2]); pk.w = f2bf(acc[i][3]);
        *reinterpret_cast<ushort4*>(qkb + (((size_t)(bh * 256 + c)) << 11) + n0 + tx * 4) = pk;
    }
}

// ---------------------------------------------------------------------------
// scores + softmax: a[b,h,n,km] = softmax_km( SCALE * sum_c qk[b,h,c,n]*xs[b,c,km,n] )
// grid: (n-chunks=32, b=8), block 256 = (hq 4) x (n 64)
// ---------------------------------------------------------------------------
__global__ __launch_bounds__(256) void score_kernel(
    const unsigned short* __restrict__ qkb, const float* __restrict__ xs,
    float* __restrict__ attf)
{
    int b = blockIdx.y;
    int tid = threadIdx.x;
    int hq = tid >> 6;
    int n = blockIdx.x * 64 + (tid & 63);
    float s[2][9] = {};
    for (int c = 0; c < 256; ++c) {
        float xv[9];
        const float* xp = xs + (((size_t)(b * 256 + c) * 9) << 11) + n;
        #pragma unroll
        for (int km = 0; km < 9; ++km) xv[km] = xp[km << 11];
        #pragma unroll
        for (int hh = 0; hh < 2; ++hh) {
            float qv = bf2f(qkb[(((size_t)((b * 8 + hq * 2 + hh) * 256 + c)) << 11) + n]);
            #pragma unroll
            for (int km = 0; km < 9; ++km) s[hh][km] += qv * xv[km];
        }
    }
    #pragma unroll
    for (int hh = 0; hh < 2; ++hh) {
        float m = -1e30f;
        #pragma unroll
        for (int km = 0; km < 9; ++km) { s[hh][km] *= SCALE_; m = fmaxf(m, s[hh][km]); }
        float den = 0.0f, a[9];
        #pragma unroll
        for (int km = 0; km < 9; ++km) { a[km] = expf(s[hh][km] - m); den += a[km]; }
        float inv = 1.0f / den;
        size_t ab = ((((size_t)(b * 8 + hq * 2 + hh)) << 11) + n) * 9;
        #pragma unroll
        for (int km = 0; km < 9; ++km) attf[ab + km] = a[km] * inv;
    }
}

// ---------------------------------------------------------------------------
// xsw[b,h,c,n] = sum_km a[b,h,n,km] * xs[b,c,km,n]  (stored bf16, same buf as qk)
// grid: (n-chunks=32, b=8), block 256 = (hq 4) x (n 64)
// ---------------------------------------------------------------------------
__global__ __launch_bounds__(256) void xsw_kernel(
    const float* __restrict__ attf, const float* __restrict__ xs,
    unsigned short* __restrict__ xswb)
{
    int b = blockIdx.y;
    int tid = threadIdx.x;
    int hq = tid >> 6;
    int n = blockIdx.x * 64 + (tid & 63);
    float a[2][9];
    #pragma unroll
    for (int hh = 0; hh < 2; ++hh) {
        size_t ab = ((((size_t)(b * 8 + hq * 2 + hh)) << 11) + n) * 9;
        #pragma unroll
        for (int km = 0; km < 9; ++km) a[hh][km] = attf[ab + km];
    }
    for (int c = 0; c < 256; ++c) {
        float xv[9];
        const float* xp = xs + (((size_t)(b * 256 + c) * 9) << 11) + n;
        #pragma unroll
        for (int km = 0; km < 9; ++km) xv[km] = xp[km << 11];
        #pragma unroll
        for (int hh = 0; hh < 2; ++hh) {
            float acc = 0.0f;
            #pragma unroll
            for (int km = 0; km < 9; ++km) acc += a[hh][km] * xv[km];
            xswb[(((size_t)((b * 8 + hq * 2 + hh) * 256 + c)) << 11) + n] = f2bf(acc);
        }
    }
}

// ---------------------------------------------------------------------------
// out[b,n, h*32+o] = sum_c Wv[h*32+o, c] * xsw[b,h,c,n] + bv[h*32+o]
// grid: (n-tiles=32, bh=64), block 256 = (ty 16: o-pairs) x (tx 16: n-quads)
// ---------------------------------------------------------------------------
__global__ __launch_bounds__(256) void outv_kernel(
    const unsigned short* __restrict__ xswb, const float* __restrict__ Wv,
    const float* __restrict__ bv, float* __restrict__ outb)
{
    int bh = blockIdx.y;
    int b = bh >> 3, h = bh & 7;
    int n0 = blockIdx.x * 64;
    __shared__ float Ws[256][33];
    __shared__ float Xs[16][64];
    int tid = threadIdx.x;
    for (int e = tid; e < 8192; e += 256) {
        int o = e >> 8, c = e & 255;
        Ws[c][o] = Wv[(size_t)(h * 32 + o) * 256 + c];
    }
    int tx = tid & 15, ty = tid >> 4;
    float acc[2][4] = {};
    for (int cb = 0; cb < 16; ++cb) {
        __syncthreads();
        for (int e = tid; e < 1024; e += 256) {
            int cc = e >> 6, nn = e & 63;
            Xs[cc][nn] = bf2f(xswb[(((size_t)(bh * 256 + cb * 16 + cc)) << 11) + n0 + nn]);
        }
        __syncthreads();
        #pragma unroll
        for (int cc = 0; cc < 16; ++cc) {
            float w0 = Ws[cb * 16 + cc][ty * 2];
            float w1 = Ws[cb * 16 + cc][ty * 2 + 1];
            float xv[4];
            #pragma unroll
            for (int k = 0; k < 4; ++k) xv[k] = Xs[cc][tx * 4 + k];
            #pragma unroll
            for (int k = 0; k < 4; ++k) {
                acc[0][k] += w0 * xv[k];
                acc[1][k] += w1 * xv[k];
            }
        }
    }
    #pragma unroll
    for (int i = 0; i < 2; ++i) {
        int o = h * 32 + ty * 2 + i;
        float bvv = bv[o];
        #pragma unroll
        for (int k = 0; k < 4; ++k)
            outb[((size_t)b * 2048 + n0 + tx * 4 + k) * 256 + o] = acc[i][k] + bvv;
    }
}

// attn.mean(0) -> (NS, KM), deterministic
__global__ __launch_bounds__(256) void attn_reduce_kernel(
    const float* __restrict__ attf, float* __restrict__ o_attn)
{
    int e = blockIdx.x * 256 + threadIdx.x;
    int n = e / 9, km = e % 9;
    float sum = 0.0f;
    for (int bh = 0; bh < 64; ++bh)
        sum += attf[(((size_t)bh << 11) + n) * 9 + km];
    o_attn[e] = sum * (1.0f / 64.0f);
}

// pred_loc = l2 @ Wl3^T + bl3  (Cout=2)
__global__ __launch_bounds__(256) void loc_kernel(
    const float* __restrict__ l2, const float* __restrict__ Wl3,
    const float* __restrict__ bl3, float* __restrict__ o_loc)
{
    int f = blockIdx.x * 256 + threadIdx.x;
    int r = f >> 1, o = f & 1;
    const float4* row = (const float4*)(l2 + (size_t)r * 256);
    const float4* wr = (const float4*)(Wl3 + (size_t)o * 256);
    float sum = bl3[o];
    for (int c = 0; c < 64; ++c) {
        float4 a = row[c], w = wr[c];
        sum += a.x * w.x + a.y * w.y + a.z * w.z + a.w * w.w;
    }
    o_loc[f] = sum;
}

// deterministic two-stage loss reductions
__global__ __launch_bounds__(256) void loss_cls_partial(
    const float* __restrict__ pred, const int* __restrict__ labels,
    float* __restrict__ partial)
{
    int tid = threadIdx.x;
    float sum = 0.0f;
    for (int e = blockIdx.x * 256 + tid; e < 4194304; e += 65536) {
        int r = e >> 8, j = e & 255;
        float p = pred[e];
        float t = (labels[r] == j) ? 1.0f : 0.0f;
        sum += fmaxf(p, 0.0f) - p * t + log1pf(expf(-fabsf(p)));
    }
    __shared__ float red[256];
    red[tid] = sum;
    __syncthreads();
    for (int w = 128; w > 0; w >>= 1) {
        if (tid < w) red[tid] += red[tid + w];
        __syncthreads();
    }
    if (tid == 0) partial[blockIdx.x] = red[0];
}

__global__ __launch_bounds__(256) void loss_loc_partial(
    const float* __restrict__ pred, const float* __restrict__ coords,
    float* __restrict__ partial)
{
    int tid = threadIdx.x;
    float sum = 0.0f;
    for (int e = blockIdx.x * 256 + tid; e < 32768; e += 65536)
        sum += fabsf(pred[e] - coords[e]);
    __shared__ float red[256];
    red[tid] = sum;
    __syncthreads();
    for (int w = 128; w > 0; w >>= 1) {
        if (tid < w) red[tid] += red[tid + w];
        __syncthreads();
    }
    if (tid == 0) partial[blockIdx.x] = red[0];
}

__global__ __launch_bounds__(256) void loss_final(
    const float* __restrict__ part, float* __restrict__ out)
{
    __shared__ float red[256];
    int t = threadIdx.x;
    red[t] = part[t];
    __syncthreads();
    for (int w = 128; w > 0; w >>= 1) {
        if (t < w) red[t] += red[t + w];
        __syncthreads();
    }
    if (t == 0) out[0] = red[0] * (1.0f / 4194304.0f);
    __syncthreads();
    red[t] = part[256 + t];
    __syncthreads();
    for (int w = 128; w > 0; w >>= 1) {
        if (t < w) red[t] += red[t + w];
        __syncthreads();
    }
    if (t == 0) out[1] = red[0] * (1.0f / 32768.0f);
}

extern "C" void kernel_launch(void* const* d_in, const int* in_sizes, int n_in,
                              void* d_out, int out_size, void* d_ws, size_t ws_size,
                              hipStream_t stream) {
    const float* x     = (const float*)d_in[0];
    const int*   idx   = (const int*)d_in[1];
    const int*   labels= (const int*)d_in[2];
    const float* coords= (const float*)d_in[3];
    const float* W_ip  = (const float*)d_in[4];
    const float* b_ip  = (const float*)d_in[5];
    const float* Wq    = (const float*)d_in[6];
    const float* bq    = (const float*)d_in[7];
    const float* Wk    = (const float*)d_in[8];
    const float* bk    = (const float*)d_in[9];
    const float* Wv    = (const float*)d_in[10];
    const float* bv    = (const float*)d_in[11];
    const float* W_dw  = (const float*)d_in[12];
    const float* b_dw  = (const float*)d_in[13];
    const float* W_pw  = (const float*)d_in[14];
    const float* Wc1   = (const float*)d_in[15];
    const float* bc1   = (const float*)d_in[16];
    const float* Wc2   = (const float*)d_in[17];
    const float* bc2   = (const float*)d_in[18];
    const float* Wc3   = (const float*)d_in[19];
    const float* bc3   = (const float*)d_in[20];
    const float* Wl1   = (const float*)d_in[21];
    const float* bl1   = (const float*)d_in[22];
    const float* Wl2   = (const float*)d_in[23];
    const float* bl2   = (const float*)d_in[24];
    const float* Wl3   = (const float*)d_in[25];
    const float* bl3   = (const float*)d_in[26];

    float* out = (float*)d_out;
    float* ws  = (float*)d_ws;

    // workspace layout (float offsets)
    float* R0   = ws;                 // x1;  later qk/xsw (bf16, spans R0+R1)
    float* R1   = ws + 8388608;       // qf
    float* R2   = ws + 16777216;      // h;  later outb (first 4.2M) + h1 (next 4.2M)
    float* posb = ws + 25165824;      // positions (1179648)
    float* qg   = ws + 26345472;      // gathered q (4194304); later MLP h2
    float* attf = ws + 30539776;      // attention weights (1179648)
    float* part = ws + 31719424;      // loss partials (512)

    unsigned short* qkb = (unsigned short*)R0;   // 33.5M bf16 over R0+R1
    float* outb = R2;
    float* h1   = R2 + 4194304;
    float* h2   = qg;

    float* o_xs   = out + 2;
    float* o_cls  = out + 37748738;
    float* o_loc  = out + 41943042;
    float* o_attn = out + 41975810;

    // 1. x1 = gelu(x @ W_ip^T)
    gemm_cp<1><<<dim3(64, 4, 8), 256, 0, stream>>>(x, W_ip, b_ip, R0, 256, 256, 4096);
    // 2. qf = x1 @ Wq^T
    gemm_cp<0><<<dim3(64, 4, 8), 256, 0, stream>>>(R0, Wq, bq, R1, 256, 256, 4096);
    // 3. h = gelu(dwconv3x3(qf))
    dwconv_kernel<<<32768, 256, 0, stream>>>(R1, W_dw, b_dw, R2);
    // 4. sampling positions
    pos_kernel<<<dim3(8, 32), 256, 0, stream>>>(R2, idx, W_pw, posb);
    // 5. q gather
    qgather_kernel<<<16384, 256, 0, stream>>>(R1, idx, qg);
    // 6. bilinear sample -> x_sampled (output)
    sample_kernel<<<147456, 256, 0, stream>>>(R0, posb, o_xs);
    // 7. qk = Wk_h^T @ q_h   (x1, qf now dead)
    qk_kernel<<<dim3(32, 4, 64), 256, 0, stream>>>(qg, Wk, qkb);
    // 8. scores + softmax
    score_kernel<<<dim3(32, 8), 256, 0, stream>>>(qkb, o_xs, attf);
    // 9. xsw = sum_km a*xs  (overwrites qk buffer)
    xsw_kernel<<<dim3(32, 8), 256, 0, stream>>>(attf, o_xs, qkb);
    // 10. out = Wv @ xsw + bv
    outv_kernel<<<dim3(32, 64), 256, 0, stream>>>(qkb, Wv, bv, outb);
    // 11. attn mean
    attn_reduce_kernel<<<72, 256, 0, stream>>>(attf, o_attn);
    // 12-14. cls MLP
    gemm_rm<2><<<dim3(256, 4), 256, 0, stream>>>(outb, Wc1, bc1, h1, 256, 256, 16384);
    gemm_rm<2><<<dim3(256, 4), 256, 0, stream>>>(h1, Wc2, bc2, h2, 256, 256, 16384);
    gemm_rm<0><<<dim3(256, 4), 256, 0, stream>>>(h2, Wc3, bc3, o_cls, 256, 256, 16384);
    // 15-17. loc MLP
    gemm_rm<2><<<dim3(256, 4), 256, 0, stream>>>(outb, Wl1, bl1, h1, 256, 256, 16384);
    gemm_rm<2><<<dim3(256, 4), 256, 0, stream>>>(h1, Wl2, bl2, h2, 256, 256, 16384);
    loc_kernel<<<128, 256, 0, stream>>>(h2, Wl3, bl3, o_loc);
    // 18-20. losses
    loss_cls_partial<<<256, 256, 0, stream>>>(o_cls, labels, part);
    loss_loc_partial<<<256, 256, 0, stream>>>(o_loc, coords, part + 256);
    loss_final<<<1, 256, 0, stream>>>(part, out);
}

// Round 3
// 699.353 us; speedup vs baseline: 4.5090x; 1.8502x over previous
//
#include <hip/hip_runtime.h>
#include <hip/hip_bf16.h>

// Problem constants
#define B_   8
#define NH_  8
#define HC_  32
#define NG_  4
#define NC_  256
#define CG_  64
#define H_   64
#define W_   64
#define HW_  4096
#define KM_  9
#define NS_  2048
#define DIMO_ 256
#define SCALE_ 0.17677669529663687f  // 32^-0.5

typedef __attribute__((ext_vector_type(4))) float f32x4;
typedef __attribute__((ext_vector_type(8))) short bf16x8;

__device__ __forceinline__ float gelu_f(float v) {
    return 0.5f * v * (1.0f + erff(v * 0.70710678118654752f));
}

__device__ __forceinline__ unsigned short f2bf(float f) {
    __hip_bfloat16 hb = __float2bfloat16(f);
    return *reinterpret_cast<unsigned short*>(&hb);
}
__device__ __forceinline__ float bf2f(unsigned short u) {
    unsigned int ui = ((unsigned int)u) << 16;
    float f;
    __builtin_memcpy(&f, &ui, 4);
    return f;
}

// ---------------------------------------------------------------------------
// Weight cast f32 -> bf16 (7 matrices of 256x256)
// ---------------------------------------------------------------------------
struct WC {
    const float* s[7];
    unsigned short* d[7];
};

__global__ __launch_bounds__(256) void wcast_kernel(WC wc) {
    int m = blockIdx.y;
    int e = blockIdx.x * 1024 + threadIdx.x * 4;
    const float4 v = *(const float4*)(wc.s[m] + e);
    ushort4 o;
    o.x = f2bf(v.x); o.y = f2bf(v.y); o.z = f2bf(v.z); o.w = f2bf(v.w);
    *(ushort4*)(wc.d[m] + e) = o;
}

// ---------------------------------------------------------------------------
// x (b, c, p) f32  ->  xt (b, p, c) bf16   (64x64 LDS tile transpose)
// grid (64 p-tiles, 4 c-tiles, 8 b)
// ---------------------------------------------------------------------------
__global__ __launch_bounds__(256) void xtk_kernel(
    const float* __restrict__ x, unsigned short* __restrict__ xt)
{
    int b = blockIdx.z;
    int c0 = blockIdx.y * 64;
    int p0 = blockIdx.x * 64;
    __shared__ float sm[64][65];
    int tid = threadIdx.x;
    #pragma unroll
    for (int rep = 0; rep < 16; ++rep) {
        int cc = (tid >> 6) + rep * 4, pp = tid & 63;
        sm[cc][pp] = x[(((size_t)(b * 256 + c0 + cc)) << 12) + p0 + pp];
    }
    __syncthreads();
    #pragma unroll
    for (int rep = 0; rep < 16; ++rep) {
        int pp = (tid >> 6) + rep * 4, cc = tid & 63;
        xt[((size_t)(b * 4096 + p0 + pp)) * 256 + c0 + cc] = f2bf(sm[cc][pp]);
    }
}

// ---------------------------------------------------------------------------
// MFMA GEMM: Y[r, o] = act(sum_k A[r,k] * W[o,k] + bias[o])
// A: R x 256 (bf16 or f32 row-major), W: 256x256 bf16 row-major,
// Y: R x 256 (bf16 or f32). Tile 128x128, BK=32, 4 waves (2x2 of 64x64).
// ---------------------------------------------------------------------------
template<int ACT, bool ASRC_F32, bool OUT_BF16>
__global__ __launch_bounds__(256) void mfma_gemm(
    const void* __restrict__ Av, const unsigned short* __restrict__ Wb,
    const float* __restrict__ bias, void* __restrict__ Yv)
{
    int r0 = blockIdx.x * 128;
    int o0 = blockIdx.y * 128;
    __shared__ unsigned short As[128][40];
    __shared__ unsigned short Bs[128][40];
    int tid = threadIdx.x;
    int lane = tid & 63;
    int wid = tid >> 6;
    int wr = (wid >> 1) * 64, wc = (wid & 1) * 64;
    int lrow = lane & 15, q = lane >> 4;
    f32x4 acc[4][4];
    #pragma unroll
    for (int i = 0; i < 4; ++i)
        #pragma unroll
        for (int j = 0; j < 4; ++j) {
            acc[i][j][0] = 0.f; acc[i][j][1] = 0.f;
            acc[i][j][2] = 0.f; acc[i][j][3] = 0.f;
        }

    int srow = tid & 127;
    int skc = (tid >> 7) * 16;

    for (int k0 = 0; k0 < 256; k0 += 32) {
        if constexpr (ASRC_F32) {
            const float* Ap = (const float*)Av + (size_t)(r0 + srow) * 256 + k0 + skc;
            unsigned short tmp[16];
            #pragma unroll
            for (int t = 0; t < 16; ++t) tmp[t] = f2bf(Ap[t]);
            *(uint4*)&As[srow][skc]     = *(uint4*)&tmp[0];
            *(uint4*)&As[srow][skc + 8] = *(uint4*)&tmp[8];
        } else {
            const unsigned short* Ap = (const unsigned short*)Av + (size_t)(r0 + srow) * 256 + k0 + skc;
            *(uint4*)&As[srow][skc]     = *(const uint4*)Ap;
            *(uint4*)&As[srow][skc + 8] = *(const uint4*)(Ap + 8);
        }
        const unsigned short* Wp = Wb + (size_t)(o0 + srow) * 256 + k0 + skc;
        *(uint4*)&Bs[srow][skc]     = *(const uint4*)Wp;
        *(uint4*)&Bs[srow][skc + 8] = *(const uint4*)(Wp + 8);
        __syncthreads();
        bf16x8 a[4], bv[4];
        #pragma unroll
        for (int i = 0; i < 4; ++i) a[i] = *(const bf16x8*)&As[wr + i * 16 + lrow][q * 8];
        #pragma unroll
        for (int j = 0; j < 4; ++j) bv[j] = *(const bf16x8*)&Bs[wc + j * 16 + lrow][q * 8];
        #pragma unroll
        for (int i = 0; i < 4; ++i)
            #pragma unroll
            for (int j = 0; j < 4; ++j)
                acc[i][j] = __builtin_amdgcn_mfma_f32_16x16x32_bf16(a[i], bv[j], acc[i][j], 0, 0, 0);
        __syncthreads();
    }

    #pragma unroll
    for (int i = 0; i < 4; ++i) {
        int rr = r0 + wr + i * 16 + q * 4;
        #pragma unroll
        for (int j = 0; j < 4; ++j) {
            int oo = o0 + wc + j * 16 + lrow;
            float bb = bias[oo];
            #pragma unroll
            for (int g2 = 0; g2 < 4; ++g2) {
                float v = acc[i][j][g2] + bb;
                if constexpr (ACT == 1) v = gelu_f(v);
                else if constexpr (ACT == 2) v = fmaxf(v, 0.0f);
                if constexpr (OUT_BF16)
                    ((unsigned short*)Yv)[(size_t)(rr + g2) * 256 + oo] = f2bf(v);
                else
                    ((float*)Yv)[(size_t)(rr + g2) * 256 + oo] = v;
            }
        }
    }
}

// ---------------------------------------------------------------------------
// Fused dwconv@gathered-points + pointwise + tanh -> positions.
// Wave per (bg, n), lane = cc.  grid (512 n-quads, 32 bg), block 256.
// ---------------------------------------------------------------------------
__global__ __launch_bounds__(256) void posk_kernel(
    const unsigned short* __restrict__ qft, const int* __restrict__ idx,
    const float* __restrict__ W_dw, const float* __restrict__ b_dw,
    const float* __restrict__ W_pw, float* __restrict__ posb)
{
    int bg = blockIdx.y;
    int b = bg >> 2, g = bg & 3;
    int tid = threadIdx.x;
    int w = tid >> 6, lane = tid & 63;
    int n = blockIdx.x * 4 + w;
    __shared__ float wpw[18 * 64];
    for (int e = tid; e < 1152; e += 256) wpw[e] = W_pw[e];
    __syncthreads();
    float wdw[9];
    #pragma unroll
    for (int k = 0; k < 9; ++k) wdw[k] = W_dw[lane * 9 + k];
    float acc = b_dw[lane];
    int yn = idx[2 * n], xn = idx[2 * n + 1];
    const unsigned short* qp = qft + (((size_t)b) << 12) * 256 + g * 64 + lane;
    #pragma unroll
    for (int ky = 0; ky < 3; ++ky) {
        int yy = yn + ky - 1;
        if (yy < 0 || yy > 63) continue;
        #pragma unroll
        for (int kx = 0; kx < 3; ++kx) {
            int xx = xn + kx - 1;
            if (xx < 0 || xx > 63) continue;
            acc += wdw[ky * 3 + kx] * bf2f(qp[(size_t)(yy * 64 + xx) * 256]);
        }
    }
    float hv = gelu_f(acc);
    float offv[18];
    #pragma unroll
    for (int o = 0; o < 18; ++o) {
        float p = wpw[o * 64 + lane] * hv;
        p += __shfl_xor(p, 1);  p += __shfl_xor(p, 2);  p += __shfl_xor(p, 4);
        p += __shfl_xor(p, 8);  p += __shfl_xor(p, 16); p += __shfl_xor(p, 32);
        offv[o] = p;
    }
    if (lane < 9) {
        int km = lane, ky = km / 3, kx = km % 3;
        int yc = yn + ky - 1; yc = yc < 0 ? 0 : (yc > 63 ? 63 : yc);
        int xc = xn + kx - 1; xc = xc < 0 ? 0 : (xc > 63 ? 63 : xc);
        float py = tanhf(offv[2 * km])     * 0.03125f + ((yc + 0.5f) * 0.03125f - 1.0f);
        float px = tanhf(offv[2 * km + 1]) * 0.03125f + ((xc + 0.5f) * 0.03125f - 1.0f);
        size_t pb = (((size_t)bg * 9 + km) * 2048 + n) * 2;
        posb[pb] = py;
        posb[pb + 1] = px;
    }
}

// ---------------------------------------------------------------------------
// Bilinear sample v2: x1t (b,p,c) bf16, position shared across 64 channels.
// grid (32 n-tiles, 36 = g*9+km, 8 b), block 256 (4 waves x 16 n each).
// ---------------------------------------------------------------------------
__global__ __launch_bounds__(256) void sample2_kernel(
    const unsigned short* __restrict__ x1t, const float* __restrict__ posb,
    float* __restrict__ o_xs)
{
    int b = blockIdx.z;
    int g = blockIdx.y / 9, km = blockIdx.y % 9;
    int n0 = blockIdx.x * 64;
    int tid = threadIdx.x;
    int w = tid >> 6, lane = tid & 63;
    int bg = b * 4 + g;
    __shared__ float sm[64][65];
    const unsigned short* img = x1t + (((size_t)b) << 12) * 256 + g * 64 + lane;
    size_t pbase = (((size_t)bg * 9 + km) * 2048 + n0) * 2;
    #pragma unroll
    for (int ii = 0; ii < 16; ++ii) {
        int nl = w * 16 + ii;
        float py = posb[pbase + nl * 2], px = posb[pbase + nl * 2 + 1];
        float ix = (px + 1.0f) * 31.5f;
        float iy = (py + 1.0f) * 31.5f;
        float x0f = floorf(ix), y0f = floorf(iy);
        float wx = ix - x0f, wy = iy - y0f;
        int xx0 = (int)x0f, yy0 = (int)y0f;
        float v = 0.0f;
        bool xv0 = (xx0 >= 0) && (xx0 <= 63);
        bool xv1 = (xx0 + 1 >= 0) && (xx0 + 1 <= 63);
        if (yy0 >= 0 && yy0 <= 63) {
            if (xv0) v += (1.0f - wx) * (1.0f - wy) * bf2f(img[(size_t)(yy0 * 64 + xx0) * 256]);
            if (xv1) v += wx * (1.0f - wy) * bf2f(img[(size_t)(yy0 * 64 + xx0 + 1) * 256]);
        }
        if (yy0 + 1 >= 0 && yy0 + 1 <= 63) {
            if (xv0) v += (1.0f - wx) * wy * bf2f(img[(size_t)((yy0 + 1) * 64 + xx0) * 256]);
            if (xv1) v += wx * wy * bf2f(img[(size_t)((yy0 + 1) * 64 + xx0 + 1) * 256]);
        }
        sm[nl][lane] = v;
    }
    __syncthreads();
    size_t obase = ((((size_t)(b * 256 + g * 64)) * 9 + km) << 11) + n0;
    #pragma unroll
    for (int rep = 0; rep < 16; ++rep) {
        int cc = (tid >> 6) + rep * 4, nn = tid & 63;
        o_xs[obase + (size_t)cc * 9 * 2048 + nn] = sm[nn][cc];
    }
}

// ---------------------------------------------------------------------------
// q gather: qft (b,p,c) bf16 -> qg (b,c,n) f32  (LDS transpose per 64-n tile)
// grid (32 n-tiles, 8 b), block 256
// ---------------------------------------------------------------------------
__global__ __launch_bounds__(256) void qgather2_kernel(
    const unsigned short* __restrict__ qft, const int* __restrict__ idx,
    float* __restrict__ qg)
{
    int b = blockIdx.y;
    int n0 = blockIdx.x * 64;
    int tid = threadIdx.x;
    __shared__ unsigned short sm[64][264];
    __shared__ int pn[64];
    if (tid < 64) pn[tid] = idx[2 * (n0 + tid)] * 64 + idx[2 * (n0 + tid) + 1];
    __syncthreads();
    #pragma unroll
    for (int rep = 0; rep < 8; ++rep) {
        int nn = (tid >> 5) + rep * 8, seg = tid & 31;
        *(uint4*)&sm[nn][seg * 8] =
            *(const uint4*)&qft[((size_t)(b * 4096) + pn[nn]) * 256 + seg * 8];
    }
    __syncthreads();
    #pragma unroll
    for (int rep = 0; rep < 64; ++rep) {
        int c = (tid >> 6) + rep * 4, nn = tid & 63;
        qg[(((size_t)(b * 256 + c)) << 11) + n0 + nn] = bf2f(sm[nn][c]);
    }
}

// ---------------------------------------------------------------------------
// qk[b,h,c,n] = sum_j q[b,h*32+j,n] * Wk[h*32+j,c]  (stored bf16)
// ---------------------------------------------------------------------------
__global__ __launch_bounds__(256) void qk_kernel(
    const float* __restrict__ qg, const float* __restrict__ Wk,
    unsigned short* __restrict__ qkb)
{
    int bh = blockIdx.z;
    int b = bh >> 3, h = bh & 7;
    int c0 = blockIdx.y * 64;
    int n0 = blockIdx.x * 64;
    __shared__ float Qs[32][64];
    __shared__ float Ws[32][65];
    int tid = threadIdx.x;
    for (int e = tid; e < 2048; e += 256) {
        int j = e >> 6, nn = e & 63;
        Qs[j][nn] = qg[(((size_t)(b * 256 + h * 32 + j)) << 11) + n0 + nn];
    }
    for (int e = tid; e < 2048; e += 256) {
        int j = e >> 6, cc = e & 63;
        Ws[j][cc] = Wk[(size_t)(h * 32 + j) * 256 + c0 + cc];
    }
    __syncthreads();
    int tx = tid & 15, ty = tid >> 4;
    float acc[4][4] = {};
    #pragma unroll
    for (int j = 0; j < 32; ++j) {
        float a[4], bb[4];
        #pragma unroll
        for (int i = 0; i < 4; ++i) a[i] = Ws[j][ty * 4 + i];
        #pragma unroll
        for (int k = 0; k < 4; ++k) bb[k] = Qs[j][tx * 4 + k];
        #pragma unroll
        for (int i = 0; i < 4; ++i)
            #pragma unroll
            for (int k = 0; k < 4; ++k)
                acc[i][k] += a[i] * bb[k];
    }
    #pragma unroll
    for (int i = 0; i < 4; ++i) {
        int c = c0 + ty * 4 + i;
        ushort4 pk;
        pk.x = f2bf(acc[i][0]); pk.y = f2bf(acc[i][1]);
        pk.z = f2bf(acc[i][2]); pk.w = f2bf(acc[i][3]);
        *reinterpret_cast<ushort4*>(qkb + (((size_t)(bh * 256 + c)) << 11) + n0 + tx * 4) = pk;
    }
}

// ---------------------------------------------------------------------------
// scores + softmax over KM
// ---------------------------------------------------------------------------
__global__ __launch_bounds__(256) void score_kernel(
    const unsigned short* __restrict__ qkb, const float* __restrict__ xs,
    float* __restrict__ attf)
{
    int b = blockIdx.y;
    int tid = threadIdx.x;
    int hq = tid >> 6;
    int n = blockIdx.x * 64 + (tid & 63);
    float s[2][9] = {};
    for (int c = 0; c < 256; ++c) {
        float xv[9];
        const float* xp = xs + (((size_t)(b * 256 + c) * 9) << 11) + n;
        #pragma unroll
        for (int km = 0; km < 9; ++km) xv[km] = xp[km << 11];
        #pragma unroll
        for (int hh = 0; hh < 2; ++hh) {
            float qv = bf2f(qkb[(((size_t)((b * 8 + hq * 2 + hh) * 256 + c)) << 11) + n]);
            #pragma unroll
            for (int km = 0; km < 9; ++km) s[hh][km] += qv * xv[km];
        }
    }
    #pragma unroll
    for (int hh = 0; hh < 2; ++hh) {
        float m = -1e30f;
        #pragma unroll
        for (int km = 0; km < 9; ++km) { s[hh][km] *= SCALE_; m = fmaxf(m, s[hh][km]); }
        float den = 0.0f, a[9];
        #pragma unroll
        for (int km = 0; km < 9; ++km) { a[km] = expf(s[hh][km] - m); den += a[km]; }
        float inv = 1.0f / den;
        size_t ab = ((((size_t)(b * 8 + hq * 2 + hh)) << 11) + n) * 9;
        #pragma unroll
        for (int km = 0; km < 9; ++km) attf[ab + km] = a[km] * inv;
    }
}

// ---------------------------------------------------------------------------
// xsw[b,h,c,n] = sum_km a[b,h,n,km] * xs[b,c,km,n]  (stored bf16)
// ---------------------------------------------------------------------------
__global__ __launch_bounds__(256) void xsw_kernel(
    const float* __restrict__ attf, const float* __restrict__ xs,
    unsigned short* __restrict__ xswb)
{
    int b = blockIdx.y;
    int tid = threadIdx.x;
    int hq = tid >> 6;
    int n = blockIdx.x * 64 + (tid & 63);
    float a[2][9];
    #pragma unroll
    for (int hh = 0; hh < 2; ++hh) {
        size_t ab = ((((size_t)(b * 8 + hq * 2 + hh)) << 11) + n) * 9;
        #pragma unroll
        for (int km = 0; km < 9; ++km) a[hh][km] = attf[ab + km];
    }
    for (int c = 0; c < 256; ++c) {
        float xv[9];
        const float* xp = xs + (((size_t)(b * 256 + c) * 9) << 11) + n;
        #pragma unroll
        for (int km = 0; km < 9; ++km) xv[km] = xp[km << 11];
        #pragma unroll
        for (int hh = 0; hh < 2; ++hh) {
            float acc = 0.0f;
            #pragma unroll
            for (int km = 0; km < 9; ++km) acc += a[hh][km] * xv[km];
            xswb[(((size_t)((b * 8 + hq * 2 + hh) * 256 + c)) << 11) + n] = f2bf(acc);
        }
    }
}

// ---------------------------------------------------------------------------
// out[b,n, h*32+o] = sum_c Wv[h*32+o, c] * xsw[b,h,c,n] + bv  -> outb f32 (r,256)
// ---------------------------------------------------------------------------
__global__ __launch_bounds__(256) void outv_kernel(
    const unsigned short* __restrict__ xswb, const float* __restrict__ Wv,
    const float* __restrict__ bv, float* __restrict__ outb)
{
    int bh = blockIdx.y;
    int b = bh >> 3, h = bh & 7;
    int n0 = blockIdx.x * 64;
    __shared__ float Ws[256][33];
    __shared__ float Xs[16][64];
    int tid = threadIdx.x;
    for (int e = tid; e < 8192; e += 256) {
        int o = e >> 8, c = e & 255;
        Ws[c][o] = Wv[(size_t)(h * 32 + o) * 256 + c];
    }
    int tx = tid & 15, ty = tid >> 4;
    float acc[2][4] = {};
    for (int cb = 0; cb < 16; ++cb) {
        __syncthreads();
        for (int e = tid; e < 1024; e += 256) {
            int cc = e >> 6, nn = e & 63;
            Xs[cc][nn] = bf2f(xswb[(((size_t)(bh * 256 + cb * 16 + cc)) << 11) + n0 + nn]);
        }
        __syncthreads();
        #pragma unroll
        for (int cc = 0; cc < 16; ++cc) {
            float w0 = Ws[cb * 16 + cc][ty * 2];
            float w1 = Ws[cb * 16 + cc][ty * 2 + 1];
            float xv[4];
            #pragma unroll
            for (int k = 0; k < 4; ++k) xv[k] = Xs[cc][tx * 4 + k];
            #pragma unroll
            for (int k = 0; k < 4; ++k) {
                acc[0][k] += w0 * xv[k];
                acc[1][k] += w1 * xv[k];
            }
        }
    }
    #pragma unroll
    for (int i = 0; i < 2; ++i) {
        int o = h * 32 + ty * 2 + i;
        float bvv = bv[o];
        #pragma unroll
        for (int k = 0; k < 4; ++k)
            outb[((size_t)b * 2048 + n0 + tx * 4 + k) * 256 + o] = acc[i][k] + bvv;
    }
}

// attn.mean(0) -> (NS, KM), deterministic
__global__ __launch_bounds__(256) void attn_reduce_kernel(
    const float* __restrict__ attf, float* __restrict__ o_attn)
{
    int e = blockIdx.x * 256 + threadIdx.x;
    int n = e / 9, km = e % 9;
    float sum = 0.0f;
    for (int bh = 0; bh < 64; ++bh)
        sum += attf[(((size_t)bh << 11) + n) * 9 + km];
    o_attn[e] = sum * (1.0f / 64.0f);
}

// pred_loc = l2 @ Wl3^T + bl3  (Cout=2), l2 in bf16
__global__ __launch_bounds__(256) void loc_kernel(
    const unsigned short* __restrict__ l2, const float* __restrict__ Wl3,
    const float* __restrict__ bl3, float* __restrict__ o_loc)
{
    int f = blockIdx.x * 256 + threadIdx.x;
    int r = f >> 1, o = f & 1;
    const unsigned short* row = l2 + (size_t)r * 256;
    const float* wr = Wl3 + (size_t)o * 256;
    float sum = bl3[o];
    for (int c = 0; c < 256; c += 8) {
        uint4 u = *(const uint4*)&row[c];
        const unsigned short* us = (const unsigned short*)&u;
        float4 w0 = *(const float4*)&wr[c];
        float4 w1 = *(const float4*)&wr[c + 4];
        sum += bf2f(us[0]) * w0.x + bf2f(us[1]) * w0.y + bf2f(us[2]) * w0.z + bf2f(us[3]) * w0.w;
        sum += bf2f(us[4]) * w1.x + bf2f(us[5]) * w1.y + bf2f(us[6]) * w1.z + bf2f(us[7]) * w1.w;
    }
    o_loc[f] = sum;
}

// deterministic two-stage loss reductions
__global__ __launch_bounds__(256) void loss_cls_partial(
    const float* __restrict__ pred, const int* __restrict__ labels,
    float* __restrict__ partial)
{
    int tid = threadIdx.x;
    float sum = 0.0f;
    for (int e = blockIdx.x * 256 + tid; e < 4194304; e += 65536) {
        int r = e >> 8, j = e & 255;
        float p = pred[e];
        float t = (labels[r] == j) ? 1.0f : 0.0f;
        sum += fmaxf(p, 0.0f) - p * t + log1pf(expf(-fabsf(p)));
    }
    __shared__ float red[256];
    red[tid] = sum;
    __syncthreads();
    for (int w = 128; w > 0; w >>= 1) {
        if (tid < w) red[tid] += red[tid + w];
        __syncthreads();
    }
    if (tid == 0) partial[blockIdx.x] = red[0];
}

__global__ __launch_bounds__(256) void loss_loc_partial(
    const float* __restrict__ pred, const float* __restrict__ coords,
    float* __restrict__ partial)
{
    int tid = threadIdx.x;
    float sum = 0.0f;
    for (int e = blockIdx.x * 256 + tid; e < 32768; e += 65536)
        sum += fabsf(pred[e] - coords[e]);
    __shared__ float red[256];
    red[tid] = sum;
    __syncthreads();
    for (int w = 128; w > 0; w >>= 1) {
        if (tid < w) red[tid] += red[tid + w];
        __syncthreads();
    }
    if (tid == 0) partial[blockIdx.x] = red[0];
}

__global__ __launch_bounds__(256) void loss_final(
    const float* __restrict__ part, float* __restrict__ out)
{
    __shared__ float red[256];
    int t = threadIdx.x;
    red[t] = part[t];
    __syncthreads();
    for (int w = 128; w > 0; w >>= 1) {
        if (t < w) red[t] += red[t + w];
        __syncthreads();
    }
    if (t == 0) out[0] = red[0] * (1.0f / 4194304.0f);
    __syncthreads();
    red[t] = part[256 + t];
    __syncthreads();
    for (int w = 128; w > 0; w >>= 1) {
        if (t < w) red[t] += red[t + w];
        __syncthreads();
    }
    if (t == 0) out[1] = red[0] * (1.0f / 32768.0f);
}

extern "C" void kernel_launch(void* const* d_in, const int* in_sizes, int n_in,
                              void* d_out, int out_size, void* d_ws, size_t ws_size,
                              hipStream_t stream) {
    const float* x     = (const float*)d_in[0];
    const int*   idx   = (const int*)d_in[1];
    const int*   labels= (const int*)d_in[2];
    const float* coords= (const float*)d_in[3];
    const float* W_ip  = (const float*)d_in[4];
    const float* b_ip  = (const float*)d_in[5];
    const float* Wq    = (const float*)d_in[6];
    const float* bq    = (const float*)d_in[7];
    const float* Wk    = (const float*)d_in[8];
    const float* bk    = (const float*)d_in[9];
    const float* Wv    = (const float*)d_in[10];
    const float* bv    = (const float*)d_in[11];
    const float* W_dw  = (const float*)d_in[12];
    const float* b_dw  = (const float*)d_in[13];
    const float* W_pw  = (const float*)d_in[14];
    const float* Wc1   = (const float*)d_in[15];
    const float* bc1   = (const float*)d_in[16];
    const float* Wc2   = (const float*)d_in[17];
    const float* bc2   = (const float*)d_in[18];
    const float* Wc3   = (const float*)d_in[19];
    const float* bc3   = (const float*)d_in[20];
    const float* Wl1   = (const float*)d_in[21];
    const float* bl1   = (const float*)d_in[22];
    const float* Wl2   = (const float*)d_in[23];
    const float* bl2   = (const float*)d_in[24];
    const float* Wl3   = (const float*)d_in[25];
    const float* bl3   = (const float*)d_in[26];

    float* out = (float*)d_out;
    float* ws  = (float*)d_ws;

    // workspace layout (f32-unit offsets), total 30,769,664 units = 123.1 MB
    unsigned short* qkb  = (unsigned short*)ws;                  // 33.55M bf16 [qk->score], then xswb
    unsigned short* xt   = (unsigned short*)(ws + 16777216);     // 8.39M bf16 [xtk->G1]
    float*          qg   = ws + 16777216;                        // 4.19M f32  [qgather->qk]
    float*          outb = ws + 16777216;                        // 4.19M f32  [outv->l1]
    unsigned short* x1t  = (unsigned short*)(ws + 20971520);     // 8.39M bf16 [G1->sample]
    unsigned short* h1   = (unsigned short*)(ws + 20971520);     // 4.19M bf16 (MLP)
    unsigned short* h2   = (unsigned short*)(ws + 20971520 + 2097152);
    unsigned short* qft  = (unsigned short*)(ws + 25165824);     // 8.39M bf16 [G2->qgather]
    float*          posb = ws + 29360128;                        // 1.18M f32 [pos->sample]
    float*          attf = ws + 29360128;                        // 1.18M f32 [score->reduce]
    unsigned short* wb   = (unsigned short*)(ws + 30539776);     // 7x65536 bf16 weights
    float*          part = ws + 30769152;                        // 512

    unsigned short* wipb = wb;
    unsigned short* wqb  = wb + 65536;
    unsigned short* wc1b = wb + 131072;
    unsigned short* wc2b = wb + 196608;
    unsigned short* wc3b = wb + 262144;
    unsigned short* wl1b = wb + 327680;
    unsigned short* wl2b = wb + 393216;

    float* o_xs   = out + 2;
    float* o_cls  = out + 37748738;
    float* o_loc  = out + 41943042;
    float* o_attn = out + 41975810;

    // 0. weight casts
    WC wc;
    wc.s[0] = W_ip; wc.d[0] = wipb;
    wc.s[1] = Wq;   wc.d[1] = wqb;
    wc.s[2] = Wc1;  wc.d[2] = wc1b;
    wc.s[3] = Wc2;  wc.d[3] = wc2b;
    wc.s[4] = Wc3;  wc.d[4] = wc3b;
    wc.s[5] = Wl1;  wc.d[5] = wl1b;
    wc.s[6] = Wl2;  wc.d[6] = wl2b;
    wcast_kernel<<<dim3(64, 7), 256, 0, stream>>>(wc);
    // 0b. x -> xt (b,p,c) bf16
    xtk_kernel<<<dim3(64, 4, 8), 256, 0, stream>>>(x, xt);
    // 1. x1t = gelu(xt @ W_ip^T + b_ip)   (b,p,c) bf16
    mfma_gemm<1, false, true><<<dim3(256, 2), 256, 0, stream>>>(xt, wipb, b_ip, x1t);
    // 2. qft = x1t @ Wq^T + bq
    mfma_gemm<0, false, true><<<dim3(256, 2), 256, 0, stream>>>(x1t, wqb, bq, qft);
    // 3. fused dwconv@points + pointwise + tanh -> positions
    posk_kernel<<<dim3(512, 32), 256, 0, stream>>>(qft, idx, W_dw, b_dw, W_pw, posb);
    // 4. bilinear sample -> x_sampled (output)   [x1t dead after]
    sample2_kernel<<<dim3(32, 36, 8), 256, 0, stream>>>(x1t, posb, o_xs);
    // 5. q gather -> qg (b,c,n) f32   [qft dead after]
    qgather2_kernel<<<dim3(32, 8), 256, 0, stream>>>(qft, idx, qg);
    // 6. qk = Wk_h^T @ q_h  [qg dead after]
    qk_kernel<<<dim3(32, 4, 64), 256, 0, stream>>>(qg, Wk, qkb);
    // 7. scores + softmax
    score_kernel<<<dim3(32, 8), 256, 0, stream>>>(qkb, o_xs, attf);
    // 8. xsw = sum_km a*xs (overwrites qkb)
    xsw_kernel<<<dim3(32, 8), 256, 0, stream>>>(attf, o_xs, qkb);
    // 9. attn mean
    attn_reduce_kernel<<<72, 256, 0, stream>>>(attf, o_attn);
    // 10. out = Wv @ xsw + bv  -> outb f32 (r,256)
    outv_kernel<<<dim3(32, 64), 256, 0, stream>>>(qkb, Wv, bv, outb);
    // 11-13. cls MLP (MFMA)
    mfma_gemm<2, true,  true ><<<dim3(128, 2), 256, 0, stream>>>(outb, wc1b, bc1, h1);
    mfma_gemm<2, false, true ><<<dim3(128, 2), 256, 0, stream>>>(h1,   wc2b, bc2, h2);
    mfma_gemm<0, false, false><<<dim3(128, 2), 256, 0, stream>>>(h2,   wc3b, bc3, o_cls);
    // 14-16. loc MLP
    mfma_gemm<2, true,  true ><<<dim3(128, 2), 256, 0, stream>>>(outb, wl1b, bl1, h1);
    mfma_gemm<2, false, true ><<<dim3(128, 2), 256, 0, stream>>>(h1,   wl2b, bl2, h2);
    loc_kernel<<<128, 256, 0, stream>>>(h2, Wl3, bl3, o_loc);
    // 17-19. losses
    loss_cls_partial<<<256, 256, 0, stream>>>(o_cls, labels, part);
    loss_loc_partial<<<256, 256, 0, stream>>>(o_loc, coords, part + 256);
    loss_final<<<1, 256, 0, stream>>>(part, out);
}

// Round 4
// 640.979 us; speedup vs baseline: 4.9197x; 1.0911x over previous
//
#include <hip/hip_runtime.h>
#include <hip/hip_bf16.h>

#define SCALE_ 0.17677669529663687f  // 32^-0.5

typedef __attribute__((ext_vector_type(4))) float f32x4;
typedef __attribute__((ext_vector_type(8))) short bf16x8;

__device__ __forceinline__ float gelu_f(float v) {
    return 0.5f * v * (1.0f + erff(v * 0.70710678118654752f));
}

__device__ __forceinline__ unsigned short f2bf(float f) {
    __hip_bfloat16 hb = __float2bfloat16(f);
    return *reinterpret_cast<unsigned short*>(&hb);
}
__device__ __forceinline__ float bf2f(unsigned short u) {
    unsigned int ui = ((unsigned int)u) << 16;
    float f;
    __builtin_memcpy(&f, &ui, 4);
    return f;
}

// ---------------------------------------------------------------------------
// Weight cast f32 -> bf16 (7 matrices of 256x256)
// ---------------------------------------------------------------------------
struct WC {
    const float* s[7];
    unsigned short* d[7];
};

__global__ __launch_bounds__(256) void wcast_kernel(WC wc) {
    int m = blockIdx.y;
    int e = blockIdx.x * 1024 + threadIdx.x * 4;
    const float4 v = *(const float4*)(wc.s[m] + e);
    ushort4 o;
    o.x = f2bf(v.x); o.y = f2bf(v.y); o.z = f2bf(v.z); o.w = f2bf(v.w);
    *(ushort4*)(wc.d[m] + e) = o;
}

// Wk (256x256) -> Wk^T bf16
__global__ __launch_bounds__(256) void wtrans_kernel(
    const float* __restrict__ Wk, unsigned short* __restrict__ wktb)
{
    int o0 = blockIdx.x * 64, c0 = blockIdx.y * 64;
    __shared__ float sm[64][65];
    int tid = threadIdx.x;
    #pragma unroll
    for (int rep = 0; rep < 16; ++rep) {
        int oo = (tid >> 6) + rep * 4, cc = tid & 63;
        sm[oo][cc] = Wk[(size_t)(o0 + oo) * 256 + c0 + cc];
    }
    __syncthreads();
    #pragma unroll
    for (int rep = 0; rep < 16; ++rep) {
        int cc = (tid >> 6) + rep * 4, oo = tid & 63;
        wktb[(size_t)(c0 + cc) * 256 + o0 + oo] = f2bf(sm[oo][cc]);
    }
}

__global__ __launch_bounds__(512) void biascat_kernel(
    const float* __restrict__ bc1, const float* __restrict__ bl1,
    float* __restrict__ bias512)
{
    int t = threadIdx.x;
    bias512[t] = (t < 256) ? bc1[t] : bl1[t - 256];
}

// ---------------------------------------------------------------------------
// x (b, c, p) f32  ->  xt (b, p, c) bf16
// ---------------------------------------------------------------------------
__global__ __launch_bounds__(256) void xtk_kernel(
    const float* __restrict__ x, unsigned short* __restrict__ xt)
{
    int b = blockIdx.z;
    int c0 = blockIdx.y * 64;
    int p0 = blockIdx.x * 64;
    __shared__ float sm[64][65];
    int tid = threadIdx.x;
    #pragma unroll
    for (int rep = 0; rep < 16; ++rep) {
        int cc = (tid >> 6) + rep * 4, pp = tid & 63;
        sm[cc][pp] = x[(((size_t)(b * 256 + c0 + cc)) << 12) + p0 + pp];
    }
    __syncthreads();
    #pragma unroll
    for (int rep = 0; rep < 16; ++rep) {
        int pp = (tid >> 6) + rep * 4, cc = tid & 63;
        xt[((size_t)(b * 4096 + p0 + pp)) * 256 + c0 + cc] = f2bf(sm[cc][pp]);
    }
}

// ---------------------------------------------------------------------------
// MFMA GEMM: Y[r, o] = act(sum_k A[r,k] * W[o,k] + bias[o]), K = 256 fixed.
// Tile 128x128, 4 waves. lda/ldy in elements.
// ---------------------------------------------------------------------------
template<int ACT, bool ASRC_F32, bool OUT_BF16>
__global__ __launch_bounds__(256) void mfma_gemm(
    const void* __restrict__ Av, int lda,
    const unsigned short* __restrict__ Wb,
    const float* __restrict__ bias, void* __restrict__ Yv, int ldy)
{
    int r0 = blockIdx.x * 128;
    int o0 = blockIdx.y * 128;
    __shared__ unsigned short As[128][40];
    __shared__ unsigned short Bs[128][40];
    int tid = threadIdx.x;
    int lane = tid & 63;
    int wid = tid >> 6;
    int wr = (wid >> 1) * 64, wc = (wid & 1) * 64;
    int lrow = lane & 15, q = lane >> 4;
    f32x4 acc[4][4];
    #pragma unroll
    for (int i = 0; i < 4; ++i)
        #pragma unroll
        for (int j = 0; j < 4; ++j) {
            acc[i][j][0] = 0.f; acc[i][j][1] = 0.f;
            acc[i][j][2] = 0.f; acc[i][j][3] = 0.f;
        }

    int srow = tid & 127;
    int skc = (tid >> 7) * 16;

    for (int k0 = 0; k0 < 256; k0 += 32) {
        if constexpr (ASRC_F32) {
            const float* Ap = (const float*)Av + (size_t)(r0 + srow) * lda + k0 + skc;
            unsigned short tmp[16];
            #pragma unroll
            for (int t = 0; t < 16; ++t) tmp[t] = f2bf(Ap[t]);
            *(uint4*)&As[srow][skc]     = *(uint4*)&tmp[0];
            *(uint4*)&As[srow][skc + 8] = *(uint4*)&tmp[8];
        } else {
            const unsigned short* Ap = (const unsigned short*)Av + (size_t)(r0 + srow) * lda + k0 + skc;
            *(uint4*)&As[srow][skc]     = *(const uint4*)Ap;
            *(uint4*)&As[srow][skc + 8] = *(const uint4*)(Ap + 8);
        }
        const unsigned short* Wp = Wb + (size_t)(o0 + srow) * 256 + k0 + skc;
        *(uint4*)&Bs[srow][skc]     = *(const uint4*)Wp;
        *(uint4*)&Bs[srow][skc + 8] = *(const uint4*)(Wp + 8);
        __syncthreads();
        bf16x8 a[4], bv[4];
        #pragma unroll
        for (int i = 0; i < 4; ++i) a[i] = *(const bf16x8*)&As[wr + i * 16 + lrow][q * 8];
        #pragma unroll
        for (int j = 0; j < 4; ++j) bv[j] = *(const bf16x8*)&Bs[wc + j * 16 + lrow][q * 8];
        #pragma unroll
        for (int i = 0; i < 4; ++i)
            #pragma unroll
            for (int j = 0; j < 4; ++j)
                acc[i][j] = __builtin_amdgcn_mfma_f32_16x16x32_bf16(a[i], bv[j], acc[i][j], 0, 0, 0);
        __syncthreads();
    }

    #pragma unroll
    for (int i = 0; i < 4; ++i) {
        int rr = r0 + wr + i * 16 + q * 4;
        #pragma unroll
        for (int j = 0; j < 4; ++j) {
            int oo = o0 + wc + j * 16 + lrow;
            float bb = bias[oo];
            #pragma unroll
            for (int g2 = 0; g2 < 4; ++g2) {
                float v = acc[i][j][g2] + bb;
                if constexpr (ACT == 1) v = gelu_f(v);
                else if constexpr (ACT == 2) v = fmaxf(v, 0.0f);
                if constexpr (OUT_BF16)
                    ((unsigned short*)Yv)[(size_t)(rr + g2) * ldy + oo] = f2bf(v);
                else
                    ((float*)Yv)[(size_t)(rr + g2) * ldy + oo] = v;
            }
        }
    }
}

// ---------------------------------------------------------------------------
// Fused dwconv@gathered-points + pointwise + tanh -> positions
// ---------------------------------------------------------------------------
__global__ __launch_bounds__(256) void posk_kernel(
    const unsigned short* __restrict__ qft, const int* __restrict__ idx,
    const float* __restrict__ W_dw, const float* __restrict__ b_dw,
    const float* __restrict__ W_pw, float* __restrict__ posb)
{
    int bg = blockIdx.y;
    int b = bg >> 2, g = bg & 3;
    int tid = threadIdx.x;
    int w = tid >> 6, lane = tid & 63;
    int n = blockIdx.x * 4 + w;
    __shared__ float wpw[18 * 64];
    for (int e = tid; e < 1152; e += 256) wpw[e] = W_pw[e];
    __syncthreads();
    float wdw[9];
    #pragma unroll
    for (int k = 0; k < 9; ++k) wdw[k] = W_dw[lane * 9 + k];
    float acc = b_dw[lane];
    int yn = idx[2 * n], xn = idx[2 * n + 1];
    const unsigned short* qp = qft + (((size_t)b) << 12) * 256 + g * 64 + lane;
    #pragma unroll
    for (int ky = 0; ky < 3; ++ky) {
        int yy = yn + ky - 1;
        if (yy < 0 || yy > 63) continue;
        #pragma unroll
        for (int kx = 0; kx < 3; ++kx) {
            int xx = xn + kx - 1;
            if (xx < 0 || xx > 63) continue;
            acc += wdw[ky * 3 + kx] * bf2f(qp[(size_t)(yy * 64 + xx) * 256]);
        }
    }
    float hv = gelu_f(acc);
    float offv[18];
    #pragma unroll
    for (int o = 0; o < 18; ++o) {
        float p = wpw[o * 64 + lane] * hv;
        p += __shfl_xor(p, 1);  p += __shfl_xor(p, 2);  p += __shfl_xor(p, 4);
        p += __shfl_xor(p, 8);  p += __shfl_xor(p, 16); p += __shfl_xor(p, 32);
        offv[o] = p;
    }
    if (lane < 9) {
        int km = lane, ky = km / 3, kx = km % 3;
        int yc = yn + ky - 1; yc = yc < 0 ? 0 : (yc > 63 ? 63 : yc);
        int xc = xn + kx - 1; xc = xc < 0 ? 0 : (xc > 63 ? 63 : xc);
        float py = tanhf(offv[2 * km])     * 0.03125f + ((yc + 0.5f) * 0.03125f - 1.0f);
        float px = tanhf(offv[2 * km + 1]) * 0.03125f + ((xc + 0.5f) * 0.03125f - 1.0f);
        size_t pb = (((size_t)bg * 9 + km) * 2048 + n) * 2;
        posb[pb] = py;
        posb[pb + 1] = px;
    }
}

// ---------------------------------------------------------------------------
// Bilinear sample v3: params for all 16 positions computed up-front (ILP).
// grid (32 n-tiles, 36 = g*9+km, 8 b), block 256 (4 waves x 16 n).
// ---------------------------------------------------------------------------
__global__ __launch_bounds__(256, 4) void sample3_kernel(
    const unsigned short* __restrict__ x1t, const float* __restrict__ posb,
    float* __restrict__ o_xs)
{
    int b = blockIdx.z;
    int g = blockIdx.y / 9, km = blockIdx.y % 9;
    int n0 = blockIdx.x * 64;
    int tid = threadIdx.x, w = tid >> 6, lane = tid & 63;
    int bg = b * 4 + g;
    __shared__ float sm[64][65];
    const unsigned short* img = x1t + (((size_t)b) << 12) * 256 + g * 64 + lane;
    int nlb = w * 16;
    size_t pb = (((size_t)bg * 9 + km) * 2048 + n0 + nlb) * 2;
    float2 P[16];
    #pragma unroll
    for (int ii = 0; ii < 16; ++ii) P[ii] = *(const float2*)&posb[pb + ii * 2];
    float v[16];
    #pragma unroll
    for (int ii = 0; ii < 16; ++ii) {
        float iy = (P[ii].x + 1.0f) * 31.5f;
        float ix = (P[ii].y + 1.0f) * 31.5f;
        float y0f = floorf(iy), x0f = floorf(ix);
        float wy = iy - y0f, wx = ix - x0f;
        int yy = (int)y0f, xx = (int)x0f;
        float w00 = (1.0f - wx) * (1.0f - wy), w01 = wx * (1.0f - wy);
        float w10 = (1.0f - wx) * wy,          w11 = wx * wy;
        bool vy0 = (yy >= 0) & (yy <= 63), vy1 = (yy >= -1) & (yy <= 62);
        bool vx0 = (xx >= 0) & (xx <= 63), vx1 = (xx >= -1) & (xx <= 62);
        if (!vy0) { w00 = 0.f; w01 = 0.f; }
        if (!vy1) { w10 = 0.f; w11 = 0.f; }
        if (!vx0) { w00 = 0.f; w10 = 0.f; }
        if (!vx1) { w01 = 0.f; w11 = 0.f; }
        int yc0 = yy < 0 ? 0 : (yy > 63 ? 63 : yy);
        int yc1 = yy + 1 < 0 ? 0 : (yy + 1 > 63 ? 63 : yy + 1);
        int xc0 = xx < 0 ? 0 : (xx > 63 ? 63 : xx);
        int xc1 = xx + 1 < 0 ? 0 : (xx + 1 > 63 ? 63 : xx + 1);
        int r0 = yc0 * 64, r1 = yc1 * 64;
        v[ii] = w00 * bf2f(img[(r0 + xc0) * 256]) + w01 * bf2f(img[(r0 + xc1) * 256])
              + w10 * bf2f(img[(r1 + xc0) * 256]) + w11 * bf2f(img[(r1 + xc1) * 256]);
    }
    #pragma unroll
    for (int ii = 0; ii < 16; ++ii) sm[nlb + ii][lane] = v[ii];
    __syncthreads();
    size_t obase = ((((size_t)(b * 256 + g * 64)) * 9 + km) << 11) + n0;
    #pragma unroll
    for (int rep = 0; rep < 16; ++rep) {
        int cc = (tid >> 6) + rep * 4, nn = tid & 63;
        o_xs[obase + (size_t)cc * 18432 + nn] = sm[nn][cc];
    }
}

// ---------------------------------------------------------------------------
// q row-gather: qft (b,p,c) bf16 -> qgt (b,n,c) bf16
// ---------------------------------------------------------------------------
__global__ __launch_bounds__(256) void qgather3_kernel(
    const unsigned short* __restrict__ qft, const int* __restrict__ idx,
    unsigned short* __restrict__ qgt)
{
    int b = blockIdx.y, n0 = blockIdx.x * 64;
    int tid = threadIdx.x;
    __shared__ int pn[64];
    if (tid < 64) pn[tid] = idx[2 * (n0 + tid)] * 64 + idx[2 * (n0 + tid) + 1];
    __syncthreads();
    for (int e = tid; e < 2048; e += 256) {
        int row = e >> 5, s = e & 31;
        *(uint4*)&qgt[((size_t)(b * 2048 + n0 + row)) * 256 + s * 8] =
            *(const uint4*)&qft[((size_t)(b * 4096 + pn[row])) * 256 + s * 8];
    }
}

// ---------------------------------------------------------------------------
// qk2[(b,nt,h,c,nn)] = sum_j Wk[h*32+j, c] * q[b, h*32+j, n]  (MFMA, K=32)
// grid (16 n-tiles, 2 c-tiles, 64 bh)
// ---------------------------------------------------------------------------
__global__ __launch_bounds__(256) void qk_mfma_kernel(
    const unsigned short* __restrict__ wktb, const unsigned short* __restrict__ qgt,
    unsigned short* __restrict__ qk2)
{
    int bh = blockIdx.z, b = bh >> 3, h = bh & 7;
    int c0 = blockIdx.y * 128;
    int n0 = blockIdx.x * 128;
    __shared__ unsigned short As[128][40];
    __shared__ unsigned short Bs[128][40];
    int tid = threadIdx.x, lane = tid & 63, wid = tid >> 6;
    int wr = (wid >> 1) * 64, wc = (wid & 1) * 64;
    int lrow = lane & 15, qd = lane >> 4;
    int srow = tid & 127, skc = (tid >> 7) * 16;
    {
        const unsigned short* Ap = wktb + (size_t)(c0 + srow) * 256 + h * 32 + skc;
        *(uint4*)&As[srow][skc]     = *(const uint4*)Ap;
        *(uint4*)&As[srow][skc + 8] = *(const uint4*)(Ap + 8);
        const unsigned short* Bp = qgt + ((size_t)(b * 2048 + n0 + srow)) * 256 + h * 32 + skc;
        *(uint4*)&Bs[srow][skc]     = *(const uint4*)Bp;
        *(uint4*)&Bs[srow][skc + 8] = *(const uint4*)(Bp + 8);
    }
    __syncthreads();
    f32x4 acc[4][4];
    #pragma unroll
    for (int i = 0; i < 4; ++i)
        #pragma unroll
        for (int j = 0; j < 4; ++j) {
            acc[i][j][0] = 0.f; acc[i][j][1] = 0.f;
            acc[i][j][2] = 0.f; acc[i][j][3] = 0.f;
        }
    bf16x8 a[4], bv[4];
    #pragma unroll
    for (int i = 0; i < 4; ++i) a[i] = *(const bf16x8*)&As[wr + i * 16 + lrow][qd * 8];
    #pragma unroll
    for (int j = 0; j < 4; ++j) bv[j] = *(const bf16x8*)&Bs[wc + j * 16 + lrow][qd * 8];
    #pragma unroll
    for (int i = 0; i < 4; ++i)
        #pragma unroll
        for (int j = 0; j < 4; ++j)
            acc[i][j] = __builtin_amdgcn_mfma_f32_16x16x32_bf16(a[i], bv[j], acc[i][j], 0, 0, 0);
    #pragma unroll
    for (int i = 0; i < 4; ++i) {
        #pragma unroll
        for (int j = 0; j < 4; ++j) {
            int n = n0 + wc + j * 16 + lrow;
            int nt = n >> 4, nn = n & 15;
            #pragma unroll
            for (int g2 = 0; g2 < 4; ++g2) {
                int c = c0 + wr + i * 16 + qd * 4 + g2;
                qk2[((size_t)((b * 128 + nt) * 8 + h)) * 4096 + c * 16 + nn] = f2bf(acc[i][j][g2]);
            }
        }
    }
}

// ---------------------------------------------------------------------------
// Fused score+softmax+xsw.  Block = (b, 16-n tile).  xs cached in LDS bf16.
// xsw written IN-PLACE into the block's own qk2 slice (layout (b,nt,h,c,nn)).
// ---------------------------------------------------------------------------
__global__ __launch_bounds__(256) void scorexsw_kernel(
    unsigned short* __restrict__ qk2, const float* __restrict__ xs,
    float* __restrict__ attf)
{
    int b = blockIdx.y, nt = blockIdx.x;
    int n0 = nt * 16;
    __shared__ unsigned short xs_s[256 * 16 * 12];  // [c][nn][12] (9 used)
    __shared__ float sred[2 * 8 * 16 * 9];
    __shared__ float a_s[8 * 16 * 9];
    int tid = threadIdx.x;

    // stage xs slice -> LDS bf16
    for (int e = tid; e < 36864; e += 256) {
        int c = e / 144, r = e % 144;
        int km = r >> 4, nn = r & 15;
        float val = xs[(((size_t)(b * 256 + c) * 9 + km) << 11) + n0 + nn];
        xs_s[(c * 16 + nn) * 12 + km] = f2bf(val);
    }
    __syncthreads();

    // phase A: scores (split c into 2 halves across waves)
    {
        int chalf = tid >> 7, h = (tid >> 4) & 7, nn = tid & 15;
        const unsigned short* qkp = qk2 + ((size_t)((b * 128 + nt) * 8 + h)) * 4096
                                    + chalf * 2048 + nn;
        float s[9] = {};
        for (int ci = 0; ci < 128; ++ci) {
            float qv = bf2f(qkp[ci * 16]);
            int cb = ((chalf * 128 + ci) * 16 + nn) * 12;
            union { uint2 u; unsigned short us[4]; } U0, U1;
            U0.u = *(const uint2*)&xs_s[cb];
            U1.u = *(const uint2*)&xs_s[cb + 4];
            unsigned short x8 = xs_s[cb + 8];
            s[0] += qv * bf2f(U0.us[0]); s[1] += qv * bf2f(U0.us[1]);
            s[2] += qv * bf2f(U0.us[2]); s[3] += qv * bf2f(U0.us[3]);
            s[4] += qv * bf2f(U1.us[0]); s[5] += qv * bf2f(U1.us[1]);
            s[6] += qv * bf2f(U1.us[2]); s[7] += qv * bf2f(U1.us[3]);
            s[8] += qv * bf2f(x8);
        }
        int sb = ((chalf * 8 + h) * 16 + nn) * 9;
        #pragma unroll
        for (int km = 0; km < 9; ++km) sred[sb + km] = s[km];
    }
    __syncthreads();
    // softmax by first 128 threads
    if (tid < 128) {
        int h = tid >> 4, nn = tid & 15;
        float t[9];
        float m = -1e30f;
        #pragma unroll
        for (int km = 0; km < 9; ++km) {
            t[km] = (sred[((0 * 8 + h) * 16 + nn) * 9 + km]
                   + sred[((1 * 8 + h) * 16 + nn) * 9 + km]) * SCALE_;
            m = fmaxf(m, t[km]);
        }
        float den = 0.0f;
        #pragma unroll
        for (int km = 0; km < 9; ++km) { t[km] = expf(t[km] - m); den += t[km]; }
        float inv = 1.0f / den;
        size_t ab = ((((size_t)(b * 8 + h)) << 11) + n0 + nn) * 9;
        #pragma unroll
        for (int km = 0; km < 9; ++km) {
            float av = t[km] * inv;
            attf[ab + km] = av;
            a_s[(h * 16 + nn) * 9 + km] = av;
        }
    }
    __syncthreads();

    // phase B: xsw (in-place over this block's qk2 slice)
    {
        int u = tid >> 4, nn = tid & 15;
        int h = u >> 1, ch = u & 1;
        float av[9];
        #pragma unroll
        for (int km = 0; km < 9; ++km) av[km] = a_s[(h * 16 + nn) * 9 + km];
        unsigned short* xw = qk2 + ((size_t)((b * 128 + nt) * 8 + h)) * 4096 + nn;
        for (int ci = 0; ci < 128; ++ci) {
            int c = ch * 128 + ci;
            int cb = (c * 16 + nn) * 12;
            union { uint2 u2; unsigned short us[4]; } U0, U1;
            U0.u2 = *(const uint2*)&xs_s[cb];
            U1.u2 = *(const uint2*)&xs_s[cb + 4];
            unsigned short x8 = xs_s[cb + 8];
            float acc = av[0] * bf2f(U0.us[0]) + av[1] * bf2f(U0.us[1])
                      + av[2] * bf2f(U0.us[2]) + av[3] * bf2f(U0.us[3])
                      + av[4] * bf2f(U1.us[0]) + av[5] * bf2f(U1.us[1])
                      + av[6] * bf2f(U1.us[2]) + av[7] * bf2f(U1.us[3])
                      + av[8] * bf2f(x8);
            xw[c * 16] = f2bf(acc);
        }
    }
}

// attn.mean(0) -> (NS, KM), deterministic
__global__ __launch_bounds__(256) void attn_reduce_kernel(
    const float* __restrict__ attf, float* __restrict__ o_attn)
{
    int e = blockIdx.x * 256 + threadIdx.x;
    int n = e / 9, km = e % 9;
    float sum = 0.0f;
    for (int bh = 0; bh < 64; ++bh)
        sum += attf[(((size_t)bh << 11) + n) * 9 + km];
    o_attn[e] = sum * (1.0f / 64.0f);
}

// ---------------------------------------------------------------------------
// out[b,n, h*32+o] = sum_c Wv[h*32+o, c] * xsw[(b,nt,h,c,nn)] + bv
// ---------------------------------------------------------------------------
__global__ __launch_bounds__(256) void outv_kernel(
    const unsigned short* __restrict__ xswb, const float* __restrict__ Wv,
    const float* __restrict__ bv, float* __restrict__ outb)
{
    int bh = blockIdx.y;
    int b = bh >> 3, h = bh & 7;
    int n0 = blockIdx.x * 64;
    __shared__ float Ws[256][33];
    __shared__ float Xs[16][64];
    int tid = threadIdx.x;
    for (int e = tid; e < 8192; e += 256) {
        int o = e >> 8, c = e & 255;
        Ws[c][o] = Wv[(size_t)(h * 32 + o) * 256 + c];
    }
    int tx = tid & 15, ty = tid >> 4;
    float acc[2][4] = {};
    for (int cb = 0; cb < 16; ++cb) {
        __syncthreads();
        for (int e = tid; e < 1024; e += 256) {
            int cc = e >> 6, nn = e & 63;
            int n = n0 + nn;
            Xs[cc][nn] = bf2f(xswb[((size_t)((b * 128 + (n >> 4)) * 8 + h)) * 4096
                                   + (cb * 16 + cc) * 16 + (n & 15)]);
        }
        __syncthreads();
        #pragma unroll
        for (int cc = 0; cc < 16; ++cc) {
            float w0 = Ws[cb * 16 + cc][ty * 2];
            float w1 = Ws[cb * 16 + cc][ty * 2 + 1];
            float xv[4];
            #pragma unroll
            for (int k = 0; k < 4; ++k) xv[k] = Xs[cc][tx * 4 + k];
            #pragma unroll
            for (int k = 0; k < 4; ++k) {
                acc[0][k] += w0 * xv[k];
                acc[1][k] += w1 * xv[k];
            }
        }
    }
    #pragma unroll
    for (int i = 0; i < 2; ++i) {
        int o = h * 32 + ty * 2 + i;
        float bvv = bv[o];
        #pragma unroll
        for (int k = 0; k < 4; ++k)
            outb[((size_t)b * 2048 + n0 + tx * 4 + k) * 256 + o] = acc[i][k] + bvv;
    }
}

// pred_loc = l2 @ Wl3^T + bl3  (Cout=2), l2 in bf16
__global__ __launch_bounds__(256) void loc_kernel(
    const unsigned short* __restrict__ l2, const float* __restrict__ Wl3,
    const float* __restrict__ bl3, float* __restrict__ o_loc)
{
    int f = blockIdx.x * 256 + threadIdx.x;
    int r = f >> 1, o = f & 1;
    const unsigned short* row = l2 + (size_t)r * 256;
    const float* wr = Wl3 + (size_t)o * 256;
    float sum = bl3[o];
    for (int c = 0; c < 256; c += 8) {
        uint4 u = *(const uint4*)&row[c];
        const unsigned short* us = (const unsigned short*)&u;
        float4 w0 = *(const float4*)&wr[c];
        float4 w1 = *(const float4*)&wr[c + 4];
        sum += bf2f(us[0]) * w0.x + bf2f(us[1]) * w0.y + bf2f(us[2]) * w0.z + bf2f(us[3]) * w0.w;
        sum += bf2f(us[4]) * w1.x + bf2f(us[5]) * w1.y + bf2f(us[6]) * w1.z + bf2f(us[7]) * w1.w;
    }
    o_loc[f] = sum;
}

// deterministic two-stage loss reductions
__global__ __launch_bounds__(256) void loss_cls_partial(
    const float* __restrict__ pred, const int* __restrict__ labels,
    float* __restrict__ partial)
{
    int tid = threadIdx.x;
    float sum = 0.0f;
    for (int e = blockIdx.x * 256 + tid; e < 4194304; e += 65536) {
        int r = e >> 8, j = e & 255;
        float p = pred[e];
        float t = (labels[r] == j) ? 1.0f : 0.0f;
        sum += fmaxf(p, 0.0f) - p * t + log1pf(expf(-fabsf(p)));
    }
    __shared__ float red[256];
    red[tid] = sum;
    __syncthreads();
    for (int w = 128; w > 0; w >>= 1) {
        if (tid < w) red[tid] += red[tid + w];
        __syncthreads();
    }
    if (tid == 0) partial[blockIdx.x] = red[0];
}

__global__ __launch_bounds__(256) void loss_loc_partial(
    const float* __restrict__ pred, const float* __restrict__ coords,
    float* __restrict__ partial)
{
    int tid = threadIdx.x;
    float sum = 0.0f;
    for (int e = blockIdx.x * 256 + tid; e < 32768; e += 65536)
        sum += fabsf(pred[e] - coords[e]);
    __shared__ float red[256];
    red[tid] = sum;
    __syncthreads();
    for (int w = 128; w > 0; w >>= 1) {
        if (tid < w) red[tid] += red[tid + w];
        __syncthreads();
    }
    if (tid == 0) partial[blockIdx.x] = red[0];
}

__global__ __launch_bounds__(256) void loss_final(
    const float* __restrict__ part, float* __restrict__ out)
{
    __shared__ float red[256];
    int t = threadIdx.x;
    red[t] = part[t];
    __syncthreads();
    for (int w = 128; w > 0; w >>= 1) {
        if (t < w) red[t] += red[t + w];
        __syncthreads();
    }
    if (t == 0) out[0] = red[0] * (1.0f / 4194304.0f);
    __syncthreads();
    red[t] = part[256 + t];
    __syncthreads();
    for (int w = 128; w > 0; w >>= 1) {
        if (t < w) red[t] += red[t + w];
        __syncthreads();
    }
    if (t == 0) out[1] = red[0] * (1.0f / 32768.0f);
}

extern "C" void kernel_launch(void* const* d_in, const int* in_sizes, int n_in,
                              void* d_out, int out_size, void* d_ws, size_t ws_size,
                              hipStream_t stream) {
    const float* x     = (const float*)d_in[0];
    const int*   idx   = (const int*)d_in[1];
    const int*   labels= (const int*)d_in[2];
    const float* coords= (const float*)d_in[3];
    const float* W_ip  = (const float*)d_in[4];
    const float* b_ip  = (const float*)d_in[5];
    const float* Wq    = (const float*)d_in[6];
    const float* bq    = (const float*)d_in[7];
    const float* Wk    = (const float*)d_in[8];
    const float* bk    = (const float*)d_in[9];
    const float* Wv    = (const float*)d_in[10];
    const float* bv    = (const float*)d_in[11];
    const float* W_dw  = (const float*)d_in[12];
    const float* b_dw  = (const float*)d_in[13];
    const float* W_pw  = (const float*)d_in[14];
    const float* Wc1   = (const float*)d_in[15];
    const float* bc1   = (const float*)d_in[16];
    const float* Wc2   = (const float*)d_in[17];
    const float* bc2   = (const float*)d_in[18];
    const float* Wc3   = (const float*)d_in[19];
    const float* bc3   = (const float*)d_in[20];
    const float* Wl1   = (const float*)d_in[21];
    const float* bl1   = (const float*)d_in[22];
    const float* Wl2   = (const float*)d_in[23];
    const float* bl2   = (const float*)d_in[24];
    const float* Wl3   = (const float*)d_in[25];
    const float* bl3   = (const float*)d_in[26];

    float* out = (float*)d_out;
    float* ws  = (float*)d_ws;

    // workspace (f32 units), total 24,511,488 units = 98.0 MB
    // Region A [0, 16,777,216): early xt/x1t/qft; then qk2/xsw; then h1/h2
    unsigned short* xt   = (unsigned short*)ws;                       // 16.8M bf16
    unsigned short* x1t  = (unsigned short*)(ws + 8388608);           // 8.4M bf16
    unsigned short* qft  = (unsigned short*)(ws + 12582912);          // 8.4M bf16
    unsigned short* qk2  = (unsigned short*)ws;                       // 33.5M bf16 (qk -> xsw in-place)
    unsigned short* h1   = (unsigned short*)ws;                       // 16384x512 bf16
    unsigned short* h2c  = (unsigned short*)(ws + 4194304);           // 16384x256 bf16
    unsigned short* h2l  = (unsigned short*)(ws + 6291456);
    unsigned short* qgt  = (unsigned short*)(ws + 16777216);          // 4.2M bf16
    float*          posb = ws + 18874368;                             // 1.18M (later attf)
    float*          attf = ws + 18874368;
    unsigned short* wktb = (unsigned short*)(ws + 20054016);          // 65536 bf16
    unsigned short* wb   = (unsigned short*)(ws + 20086784);          // 7x65536 bf16
    float*          b512 = ws + 20316160;                             // 512
    float*          part = ws + 20316672;                             // 512
    float*          outb = ws + 20317184;                             // 4.2M f32

    unsigned short* wipb = wb;
    unsigned short* wqb  = wb + 65536;
    unsigned short* wc1b = wb + 131072;   // wl1 adjacent -> merged 512-row weight
    unsigned short* wl1b = wb + 196608;
    unsigned short* wc2b = wb + 262144;
    unsigned short* wl2b = wb + 327680;
    unsigned short* wc3b = wb + 393216;
    (void)wl1b;

    float* o_xs   = out + 2;
    float* o_cls  = out + 37748738;
    float* o_loc  = out + 41943042;
    float* o_attn = out + 41975810;

    // 0. weight casts + Wk^T + merged bias
    WC wc;
    wc.s[0] = W_ip; wc.d[0] = wipb;
    wc.s[1] = Wq;   wc.d[1] = wqb;
    wc.s[2] = Wc1;  wc.d[2] = wc1b;
    wc.s[3] = Wl1;  wc.d[3] = wl1b;
    wc.s[4] = Wc2;  wc.d[4] = wc2b;
    wc.s[5] = Wl2;  wc.d[5] = wl2b;
    wc.s[6] = Wc3;  wc.d[6] = wc3b;
    wcast_kernel<<<dim3(64, 7), 256, 0, stream>>>(wc);
    wtrans_kernel<<<dim3(4, 4), 256, 0, stream>>>(Wk, wktb);
    biascat_kernel<<<1, 512, 0, stream>>>(bc1, bl1, b512);
    // 0b. x -> xt (b,p,c) bf16
    xtk_kernel<<<dim3(64, 4, 8), 256, 0, stream>>>(x, xt);
    // 1. x1t = gelu(xt @ W_ip^T + b_ip)
    mfma_gemm<1, false, true><<<dim3(256, 2), 256, 0, stream>>>(xt, 256, wipb, b_ip, x1t, 256);
    // 2. qft = x1t @ Wq^T + bq
    mfma_gemm<0, false, true><<<dim3(256, 2), 256, 0, stream>>>(x1t, 256, wqb, bq, qft, 256);
    // 3. positions (fused dwconv + pointwise + tanh at gathered points)
    posk_kernel<<<dim3(512, 32), 256, 0, stream>>>(qft, idx, W_dw, b_dw, W_pw, posb);
    // 4. bilinear sample -> x_sampled (output)
    sample3_kernel<<<dim3(32, 36, 8), 256, 0, stream>>>(x1t, posb, o_xs);
    // 5. q row-gather -> qgt (b,n,c) bf16
    qgather3_kernel<<<dim3(32, 8), 256, 0, stream>>>(qft, idx, qgt);
    // 6. qk (MFMA) -> qk2 (b,nt,h,c,nn)   [xt/x1t/qft dead now]
    qk_mfma_kernel<<<dim3(16, 2, 64), 256, 0, stream>>>(wktb, qgt, qk2);
    // 7. fused scores + softmax + xsw (in-place in qk2)
    scorexsw_kernel<<<dim3(128, 8), 256, 0, stream>>>(qk2, o_xs, attf);
    // 8. attn mean
    attn_reduce_kernel<<<72, 256, 0, stream>>>(attf, o_attn);
    // 9. out = Wv @ xsw + bv -> outb f32 (B*NS, 256)
    outv_kernel<<<dim3(32, 64), 256, 0, stream>>>(qk2, Wv, bv, outb);
    // 10. merged MLP layer 1 (cls||loc) -> h1 (16384 x 512)
    mfma_gemm<2, true, true><<<dim3(128, 4), 256, 0, stream>>>(outb, 256, wc1b, b512, h1, 512);
    // 11-12. layer 2
    mfma_gemm<2, false, true><<<dim3(128, 2), 256, 0, stream>>>(h1, 512, wc2b, bc2, h2c, 256);
    mfma_gemm<2, false, true><<<dim3(128, 2), 256, 0, stream>>>(h1 + 256, 512, wl2b, bl2, h2l, 256);
    // 13. cls layer 3 -> o_cls
    mfma_gemm<0, false, false><<<dim3(128, 2), 256, 0, stream>>>(h2c, 256, wc3b, bc3, o_cls, 256);
    // 14. loc layer 3
    loc_kernel<<<128, 256, 0, stream>>>(h2l, Wl3, bl3, o_loc);
    // 15-17. losses
    loss_cls_partial<<<256, 256, 0, stream>>>(o_cls, labels, part);
    loss_loc_partial<<<256, 256, 0, stream>>>(o_loc, coords, part + 256);
    loss_final<<<1, 256, 0, stream>>>(part, out);
}